// Round 4
// baseline (807.936 us; speedup 1.0000x reference)
//
#include <hip/hip_runtime.h>
#include <stdint.h>
#include <stddef.h>

enum { EPI_SPLIT = 0, EPI_SOFTPLUS = 1, EPI_OUT = 2, EPI_PARTIAL = 3 };

// C[m,n] = sum_k A[m,k] * B[n,k]  -- all fp32, VALU only (validation round, no
// MFMA / bf16 assumptions). Block 256 = 16x16 threads, each computes
// (BM/16)x(BN/16) outputs at rows ty+16i, cols tx+16j. LDS stride BK+4 keeps
// float4 alignment (144B rows) and spreads banks (2-way worst case).
template<int BM, int BN, int BK, int EPI>
__global__ __launch_bounds__(256)
void gemm32(const float* __restrict__ A, int lda,
            const float* __restrict__ B, int ldb,
            float* __restrict__ out0, float* __restrict__ out1,
            const float* __restrict__ bias,
            int N, int kchunk)
{
    constexpr int TMI = BM / 16;
    constexpr int TNJ = BN / 16;
    constexpr int AS  = BK + 4;
    constexpr int CA  = BM * BK / 4 / 256;   // float4 chunks/thread for A tile
    constexpr int CB  = BN * BK / 4 / 256;
    constexpr int CPR = BK / 4;              // float4 chunks per row
    static_assert(BM * BK % 1024 == 0 && BN * BK % 1024 == 0, "stage");

    __shared__ __align__(16) float As[BM * AS];
    __shared__ __align__(16) float Bs[BN * AS];

    const int tid = threadIdx.x;
    const int tx  = tid & 15;
    const int ty  = tid >> 4;
    const int m0  = blockIdx.x * BM;
    const int n0  = blockIdx.y * BN;
    const int ks  = blockIdx.z;
    const int kbeg = ks * kchunk;

    float acc[TMI][TNJ];
#pragma unroll
    for (int i = 0; i < TMI; i++)
#pragma unroll
        for (int j = 0; j < TNJ; j++) acc[i][j] = 0.f;

    for (int kb = kbeg; kb < kbeg + kchunk; kb += BK) {
        __syncthreads();
#pragma unroll
        for (int i = 0; i < CA; i++) {
            int c = i * 256 + tid;
            int r = c / CPR, kc = (c % CPR) * 4;
            float4 v = *reinterpret_cast<const float4*>(A + (size_t)(m0 + r) * lda + kb + kc);
            *reinterpret_cast<float4*>(&As[r * AS + kc]) = v;
        }
#pragma unroll
        for (int i = 0; i < CB; i++) {
            int c = i * 256 + tid;
            int r = c / CPR, kc = (c % CPR) * 4;
            float4 v = *reinterpret_cast<const float4*>(B + (size_t)(n0 + r) * ldb + kb + kc);
            *reinterpret_cast<float4*>(&Bs[r * AS + kc]) = v;
        }
        __syncthreads();
#pragma unroll
        for (int kk = 0; kk < BK; kk += 4) {
            float4 a4[TMI], b4[TNJ];
#pragma unroll
            for (int i = 0; i < TMI; i++)
                a4[i] = *reinterpret_cast<const float4*>(&As[(ty + i * 16) * AS + kk]);
#pragma unroll
            for (int j = 0; j < TNJ; j++)
                b4[j] = *reinterpret_cast<const float4*>(&Bs[(tx + j * 16) * AS + kk]);
#pragma unroll
            for (int i = 0; i < TMI; i++)
#pragma unroll
                for (int j = 0; j < TNJ; j++) {
                    acc[i][j] = fmaf(a4[i].x, b4[j].x, acc[i][j]);
                    acc[i][j] = fmaf(a4[i].y, b4[j].y, acc[i][j]);
                    acc[i][j] = fmaf(a4[i].z, b4[j].z, acc[i][j]);
                    acc[i][j] = fmaf(a4[i].w, b4[j].w, acc[i][j]);
                }
        }
    }

#pragma unroll
    for (int i = 0; i < TMI; i++) {
#pragma unroll
        for (int j = 0; j < TNJ; j++) {
            int row = m0 + ty + i * 16;
            int col = n0 + tx + j * 16;
            float val = acc[i][j];
            if (EPI == EPI_SPLIT) {
                val += bias[col];
                if (col < 2048) out0[(size_t)row * 2048 + col] = val;
                else            out1[(size_t)row * 2048 + col - 2048] = val;
            } else if (EPI == EPI_SOFTPLUS) {
                val += bias[col];
                float sp = (val > 15.f) ? val : log1pf(__expf(val));
                out0[(size_t)row * N + col] = sp;
            } else if (EPI == EPI_OUT) {
                val += bias[col];
                out0[(size_t)row * N + col] = val;
            } else { // EPI_PARTIAL: split-K partials [ks][m][96]
                out0[((size_t)ks * 2048 + row) * 96 + col] = val;
            }
        }
    }
}

// depthwise causal conv (k=3) + silu, all fp32.
__global__ __launch_bounds__(256)
void conv_silu(const float* __restrict__ xc, const float* __restrict__ cw,
               const float* __restrict__ cb, float* __restrict__ uf)
{
    int id = blockIdx.x * 256 + threadIdx.x;   // 2048 * 512
    int m  = id >> 9;
    int d4 = (id & 511) * 4;
    int l  = m & 1023;

    const float4 zero = make_float4(0.f, 0.f, 0.f, 0.f);
    float4 a = *reinterpret_cast<const float4*>(xc + (size_t)m * 2048 + d4);
    float4 b = (l >= 1) ? *reinterpret_cast<const float4*>(xc + (size_t)(m - 1) * 2048 + d4) : zero;
    float4 c = (l >= 2) ? *reinterpret_cast<const float4*>(xc + (size_t)(m - 2) * 2048 + d4) : zero;

    float av[4] = {a.x, a.y, a.z, a.w};
    float bv[4] = {b.x, b.y, b.z, b.w};
    float cv[4] = {c.x, c.y, c.z, c.w};
    float4 o;
    float* ov = &o.x;
#pragma unroll
    for (int j = 0; j < 4; j++) {
        int d = d4 + j;
        float v = cb[d] + cw[d * 3 + 0] * cv[j] + cw[d * 3 + 1] * bv[j] + cw[d * 3 + 2] * av[j];
        ov[j] = v / (1.f + __expf(-v));
    }
    *reinterpret_cast<float4*>(uf + (size_t)m * 2048 + d4) = o;
}

// reduce split-K=8 partials -> xp fp32 (2048 x 96) and dlt fp32 (2048 x 64)
__global__ __launch_bounds__(256)
void xp_reduce(const float* __restrict__ part, float* __restrict__ xp, float* __restrict__ dlt)
{
    int e = blockIdx.x * 256 + threadIdx.x;    // < 2048*96 exactly
    float s = 0.f;
#pragma unroll
    for (int ks = 0; ks < 8; ks++) s += part[(size_t)ks * 2048 * 96 + e];
    xp[e] = s;
    int n = e % 96, m = e / 96;
    if (n < 64) dlt[(size_t)m * 64 + n] = s;
}

// chunked selective scan fused with y * silu(res). One wave = 4 channels x 16 states.
__global__ __launch_bounds__(256)
void scan_kernel(const float* __restrict__ delta, const float* __restrict__ uf,
                 const float* __restrict__ xp, const float* __restrict__ A_log,
                 const float* __restrict__ res, float* __restrict__ yg)
{
    __shared__ __align__(16) float Bsh[256 * 16];
    __shared__ __align__(16) float Csh[256 * 16];
    const int tid = threadIdx.x;
    const int dtile = blockIdx.x;          // 0..127 -> 16 channels
    const int cchunk = blockIdx.y;         // 0..3
    const int b = blockIdx.z;              // 0..1
    const int mbase = b * 1024 + cchunk * 256;

    {   // stage B (xp cols 64..79) and C (cols 80..95) for all 256 tokens
        const float4* rp4 = reinterpret_cast<const float4*>(xp + (size_t)(mbase + tid) * 96 + 64);
        float4* bd = reinterpret_cast<float4*>(&Bsh[tid * 16]);
        float4* cd = reinterpret_cast<float4*>(&Csh[tid * 16]);
        bd[0] = rp4[0]; bd[1] = rp4[1]; bd[2] = rp4[2]; bd[3] = rp4[3];
        cd[0] = rp4[4]; cd[1] = rp4[5]; cd[2] = rp4[6]; cd[3] = rp4[7];
    }
    __syncthreads();

    const int w = tid >> 6;
    const int lane = tid & 63;
    const int n = lane & 15;
    const int dl = lane >> 4;
    const int d = dtile * 16 + w * 4 + dl;

    const float Aval = -__expf(A_log[d * 16 + n]);
    float s = 0.f;

    for (int t = 0; t < 256; t++) {
        size_t idx = (size_t)(mbase + t) * 2048 + d;
        float dv = delta[idx];
        float uv = uf[idx];
        float dA = __expf(dv * Aval);
        s = fmaf(dA, s, dv * Bsh[t * 16 + n] * uv);
        float p = s * Csh[t * 16 + n];
        p += __shfl_xor(p, 1);
        p += __shfl_xor(p, 2);
        p += __shfl_xor(p, 4);
        p += __shfl_xor(p, 8);
        if (n == 0) {
            float r = res[idx];
            float sr = r / (1.f + __expf(-r));
            yg[idx] = p * sr;
        }
    }
}

extern "C" void kernel_launch(void* const* d_in, const int* in_sizes, int n_in,
                              void* d_out, int out_size, void* d_ws, size_t ws_size,
                              hipStream_t stream)
{
    const float* x      = (const float*)d_in[0];   // (2,1024,1024) fp32
    const float* W_in   = (const float*)d_in[1];   // (4096,1024)
    const float* b_in   = (const float*)d_in[2];   // (4096,)
    const float* conv_w = (const float*)d_in[3];   // (2048,1,3)
    const float* conv_b = (const float*)d_in[4];   // (2048,)
    const float* W_x    = (const float*)d_in[5];   // (96,2048)
    const float* W_dt   = (const float*)d_in[6];   // (2048,64)
    const float* b_dt   = (const float*)d_in[7];   // (2048,)
    const float* A_log  = (const float*)d_in[8];   // (2048,16)
    const float* W_out  = (const float*)d_in[9];   // (1024,2048)
    const float* b_out  = (const float*)d_in[10];  // (1024,)
    float* out = (float*)d_out;                    // (2,1024,1024) fp32

    // Workspace ~71.6 MB, all fp32. delta aliases xc (dead after conv).
    char* p = (char*)d_ws;
    auto alloc = [&](size_t bytes) { char* r = p; p += (bytes + 255) & ~(size_t)255; return r; };
    float* xc    = (float*)alloc(2048ull * 2048 * 4);   // 16 MB (later: delta)
    float* res   = (float*)alloc(2048ull * 2048 * 4);   // 16 MB
    float* uf    = (float*)alloc(2048ull * 2048 * 4);   // 16 MB
    float* xpp   = (float*)alloc(8ull * 2048 * 96 * 4); // 6.3 MB
    float* xp    = (float*)alloc(2048ull * 96 * 4);
    float* dlt   = (float*)alloc(2048ull * 64 * 4);
    float* yg    = (float*)alloc(2048ull * 2048 * 4);   // 16 MB
    float* delta = xc;                                  // alias

    // 1. in_proj: xr = x @ W_in^T + b_in -> xc | res
    gemm32<64, 64, 32, EPI_SPLIT><<<dim3(32, 64), 256, 0, stream>>>(
        x, 1024, W_in, 1024, xc, res, b_in, 4096, 1024);

    // 2. depthwise causal conv + silu -> uf
    conv_silu<<<4096, 256, 0, stream>>>(xc, conv_w, conv_b, uf);

    // 3. x_proj: xp = u @ W_x^T (split-K=8 partials)
    gemm32<64, 96, 32, EPI_PARTIAL><<<dim3(32, 1, 8), 256, 0, stream>>>(
        uf, 2048, W_x, 2048, xpp, nullptr, nullptr, 96, 256);

    // 4. reduce partials -> xp, dlt
    xp_reduce<<<768, 256, 0, stream>>>(xpp, xp, dlt);

    // 5. dt_proj: delta = softplus(dlt @ W_dt^T + b_dt)
    gemm32<64, 64, 32, EPI_SOFTPLUS><<<dim3(32, 32), 256, 0, stream>>>(
        dlt, 64, W_dt, 64, delta, nullptr, b_dt, 2048, 64);

    // 6. chunked scan + silu(res) gating -> yg
    scan_kernel<<<dim3(128, 4, 2), 256, 0, stream>>>(delta, uf, xp, A_log, res, yg);

    // 7. out_proj: out = yg @ W_out^T + b_out (fp32 out)
    gemm32<64, 64, 32, EPI_OUT><<<dim3(32, 16), 256, 0, stream>>>(
        yg, 2048, W_out, 2048, out, nullptr, b_out, 1024, 2048);
}

// Round 5
// 423.665 us; speedup vs baseline: 1.9070x; 1.9070x over previous
//
#include <hip/hip_runtime.h>
#include <stdint.h>
#include <stddef.h>

typedef __attribute__((ext_vector_type(8))) short short8;
typedef __attribute__((ext_vector_type(4))) float floatx4;
typedef unsigned short ushort_t;

__device__ __forceinline__ ushort_t f2bf(float f) {
    union { float f; uint32_t u; } v; v.f = f;
    return (ushort_t)((v.u + 0x7fffu + ((v.u >> 16) & 1u)) >> 16);
}
__device__ __forceinline__ float bf2f(ushort_t u) {
    union { uint32_t u; float f; } v; v.u = ((uint32_t)u) << 16; return v.f;
}

enum { EPI_SPLIT = 0, EPI_SOFTPLUS = 1, EPI_OUT = 2, EPI_PARTIAL = 3 };

// Convert x + 4 weights fp32 -> bf16 in one launch.
// float4 boundaries: x 524288 | W_in 1048576 | W_x 49152 | W_dt 32768 | W_out 524288
__global__ __launch_bounds__(256)
void cvt5(const float* __restrict__ x, const float* __restrict__ win,
          const float* __restrict__ wx, const float* __restrict__ wdt,
          const float* __restrict__ wout,
          ushort_t* __restrict__ xb, ushort_t* __restrict__ winb,
          ushort_t* __restrict__ wxb, ushort_t* __restrict__ wdtb,
          ushort_t* __restrict__ woutb)
{
    int g = blockIdx.x * 256 + threadIdx.x;   // < 2179072 exactly
    const float* s; ushort_t* d; int off;
    if      (g < 524288)  { s = x;    d = xb;    off = g; }
    else if (g < 1572864) { s = win;  d = winb;  off = g - 524288; }
    else if (g < 1622016) { s = wx;   d = wxb;   off = g - 1572864; }
    else if (g < 1654784) { s = wdt;  d = wdtb;  off = g - 1622016; }
    else                  { s = wout; d = woutb; off = g - 1654784; }
    float4 v = reinterpret_cast<const float4*>(s)[off];
    union { ushort_t u[4]; uint2 q; } o;
    o.u[0] = f2bf(v.x); o.u[1] = f2bf(v.y); o.u[2] = f2bf(v.z); o.u[3] = f2bf(v.w);
    *reinterpret_cast<uint2*>(d + (size_t)off * 4) = o.q;
}

// C[m,n] = sum_k A[m,k] * B[n,k]  (bf16 operands, fp32 accum, fp32 outputs)
// Block: 256 threads = 4 waves arranged WR x WC. Wave tile (BM/WR) x (BN/WC).
// MFMA 16x16x32 bf16. A-frag: lane holds row m=lane&15, k=(lane>>4)*8+j.
// B-frag: row n=lane&15, same k. C/D: col=lane&15, row=(lane>>4)*4+reg.
template<int BM, int BN, int BK, int WR, int WC, int EPI>
__global__ __launch_bounds__(256)
void gemm_bt(const ushort_t* __restrict__ A, int lda,
             const ushort_t* __restrict__ Bw, int ldb,
             float* __restrict__ out0, float* __restrict__ out1,
             const float* __restrict__ bias,
             int N, int kchunk)
{
    constexpr int TM = BM / WR / 16;
    constexpr int TN = BN / WC / 16;
    static_assert(BM % (WR * 16) == 0 && BN % (WC * 16) == 0, "tile");
    static_assert((BM * BK) % 2048 == 0 && (BN * BK) % 2048 == 0, "stage");

    __shared__ __align__(16) short As[BM * BK];
    __shared__ __align__(16) short Bs[BN * BK];

    const int tid  = threadIdx.x;
    const int m0   = blockIdx.x * BM;
    const int n0   = blockIdx.y * BN;
    const int ks   = blockIdx.z;
    const int kbeg = ks * kchunk;

    const int w    = tid >> 6;
    const int lane = tid & 63;
    const int quad = lane >> 4;
    const int l16  = lane & 15;
    const int wr   = w / WC, wc = w % WC;
    const int wm   = wr * (BM / WR);
    const int wn   = wc * (BN / WC);

    floatx4 acc[TM][TN];
#pragma unroll
    for (int i = 0; i < TM; i++)
#pragma unroll
        for (int j = 0; j < TN; j++) acc[i][j] = (floatx4){0.f, 0.f, 0.f, 0.f};

    constexpr int nA = BM * BK / 2048;  // 16B chunks per thread
    constexpr int nB = BN * BK / 2048;
    constexpr int CPR = BK / 8;         // 16B chunks per row

    for (int kb = kbeg; kb < kbeg + kchunk; kb += BK) {
        __syncthreads();
#pragma unroll
        for (int i = 0; i < nA; i++) {
            int c = i * 256 + tid;
            int r = c / CPR, kc = (c % CPR) * 8;
            short8 v = *reinterpret_cast<const short8*>(A + (size_t)(m0 + r) * lda + kb + kc);
            *reinterpret_cast<short8*>(&As[r * BK + kc]) = v;
        }
#pragma unroll
        for (int i = 0; i < nB; i++) {
            int c = i * 256 + tid;
            int r = c / CPR, kc = (c % CPR) * 8;
            short8 v = *reinterpret_cast<const short8*>(Bw + (size_t)(n0 + r) * ldb + kb + kc);
            *reinterpret_cast<short8*>(&Bs[r * BK + kc]) = v;
        }
        __syncthreads();
#pragma unroll
        for (int kk = 0; kk < BK / 32; kk++) {
            short8 af[TM], bfr[TN];
#pragma unroll
            for (int t = 0; t < TM; t++)
                af[t] = *reinterpret_cast<const short8*>(&As[(wm + t * 16 + l16) * BK + kk * 32 + quad * 8]);
#pragma unroll
            for (int u2 = 0; u2 < TN; u2++)
                bfr[u2] = *reinterpret_cast<const short8*>(&Bs[(wn + u2 * 16 + l16) * BK + kk * 32 + quad * 8]);
#pragma unroll
            for (int t = 0; t < TM; t++)
#pragma unroll
                for (int u2 = 0; u2 < TN; u2++)
                    acc[t][u2] = __builtin_amdgcn_mfma_f32_16x16x32_bf16(af[t], bfr[u2], acc[t][u2], 0, 0, 0);
        }
    }

#pragma unroll
    for (int t = 0; t < TM; t++) {
#pragma unroll
        for (int u2 = 0; u2 < TN; u2++) {
#pragma unroll
            for (int r = 0; r < 4; r++) {
                int row = m0 + wm + t * 16 + quad * 4 + r;
                int col = n0 + wn + u2 * 16 + l16;
                float val = acc[t][u2][r];
                if (EPI == EPI_SPLIT) {
                    val += bias[col];
                    if (col < 2048) out0[(size_t)row * 2048 + col] = val;
                    else            out1[(size_t)row * 2048 + col - 2048] = val;
                } else if (EPI == EPI_SOFTPLUS) {
                    val += bias[col];
                    float sp = (val > 15.f) ? val : log1pf(__expf(val));
                    out0[(size_t)row * N + col] = sp;
                } else if (EPI == EPI_OUT) {
                    val += bias[col];
                    out0[(size_t)row * N + col] = val;
                } else { // EPI_PARTIAL: split-K partials [ks][m][96]
                    out0[((size_t)ks * 2048 + row) * 96 + col] = val;
                }
            }
        }
    }
}

// depthwise causal conv (k=3) + silu. fp32 in, bf16 out (feeds x_proj GEMM + scan).
__global__ __launch_bounds__(256)
void conv_silu(const float* __restrict__ xc, const float* __restrict__ cw,
               const float* __restrict__ cb, ushort_t* __restrict__ ub)
{
    int id = blockIdx.x * 256 + threadIdx.x;   // 2048 * 512
    int m  = id >> 9;
    int d4 = (id & 511) * 4;
    int l  = m & 1023;

    const float4 zero = make_float4(0.f, 0.f, 0.f, 0.f);
    float4 a = *reinterpret_cast<const float4*>(xc + (size_t)m * 2048 + d4);
    float4 b = (l >= 1) ? *reinterpret_cast<const float4*>(xc + (size_t)(m - 1) * 2048 + d4) : zero;
    float4 c = (l >= 2) ? *reinterpret_cast<const float4*>(xc + (size_t)(m - 2) * 2048 + d4) : zero;

    float av[4] = {a.x, a.y, a.z, a.w};
    float bv[4] = {b.x, b.y, b.z, b.w};
    float cv[4] = {c.x, c.y, c.z, c.w};
    union { ushort_t u[4]; uint2 q; } o;
#pragma unroll
    for (int j = 0; j < 4; j++) {
        int d = d4 + j;
        float v = cb[d] + cw[d * 3 + 0] * cv[j] + cw[d * 3 + 1] * bv[j] + cw[d * 3 + 2] * av[j];
        o.u[j] = f2bf(v / (1.f + __expf(-v)));
    }
    *reinterpret_cast<uint2*>(ub + (size_t)m * 2048 + d4) = o.q;
}

// reduce split-K=4 partials -> xp fp32 (2048 x 96) and dlt bf16 (2048 x 64)
__global__ __launch_bounds__(256)
void xp_reduce(const float* __restrict__ part, float* __restrict__ xp, ushort_t* __restrict__ dltb)
{
    int e = blockIdx.x * 256 + threadIdx.x;    // < 2048*96 exactly
    float s = 0.f;
#pragma unroll
    for (int ks = 0; ks < 4; ks++) s += part[(size_t)ks * 2048 * 96 + e];
    xp[e] = s;
    int n = e % 96, m = e / 96;
    if (n < 64) dltb[(size_t)m * 64 + n] = f2bf(s);
}

// chunked selective scan fused with y * silu(res). One wave = 4 channels x 16 states.
__global__ __launch_bounds__(256)
void scan_kernel(const float* __restrict__ delta, const ushort_t* __restrict__ ub,
                 const float* __restrict__ xp, const float* __restrict__ A_log,
                 const float* __restrict__ res, ushort_t* __restrict__ ygb)
{
    __shared__ __align__(16) float Bsh[256 * 16];
    __shared__ __align__(16) float Csh[256 * 16];
    const int tid = threadIdx.x;
    const int dtile = blockIdx.x;          // 0..127 -> 16 channels
    const int cchunk = blockIdx.y;         // 0..3
    const int b = blockIdx.z;              // 0..1
    const int mbase = b * 1024 + cchunk * 256;

    {   // stage B (xp cols 64..79) and C (cols 80..95) for all 256 tokens
        const float4* rp4 = reinterpret_cast<const float4*>(xp + (size_t)(mbase + tid) * 96 + 64);
        float4* bd = reinterpret_cast<float4*>(&Bsh[tid * 16]);
        float4* cd = reinterpret_cast<float4*>(&Csh[tid * 16]);
        bd[0] = rp4[0]; bd[1] = rp4[1]; bd[2] = rp4[2]; bd[3] = rp4[3];
        cd[0] = rp4[4]; cd[1] = rp4[5]; cd[2] = rp4[6]; cd[3] = rp4[7];
    }
    __syncthreads();

    const int w = tid >> 6;
    const int lane = tid & 63;
    const int n = lane & 15;
    const int dl = lane >> 4;
    const int d = dtile * 16 + w * 4 + dl;

    const float Aval = -__expf(A_log[d * 16 + n]);
    float s = 0.f;

    for (int t = 0; t < 256; t++) {
        size_t idx = (size_t)(mbase + t) * 2048 + d;
        float dv = delta[idx];
        float uv = bf2f(ub[idx]);
        float dA = __expf(dv * Aval);
        s = fmaf(dA, s, dv * Bsh[t * 16 + n] * uv);
        float p = s * Csh[t * 16 + n];
        p += __shfl_xor(p, 1);
        p += __shfl_xor(p, 2);
        p += __shfl_xor(p, 4);
        p += __shfl_xor(p, 8);
        if (n == 0) {
            float r = res[idx];
            float sr = r / (1.f + __expf(-r));
            ygb[idx] = f2bf(p * sr);
        }
    }
}

extern "C" void kernel_launch(void* const* d_in, const int* in_sizes, int n_in,
                              void* d_out, int out_size, void* d_ws, size_t ws_size,
                              hipStream_t stream)
{
    const float* x      = (const float*)d_in[0];   // (2,1024,1024) fp32
    const float* W_in   = (const float*)d_in[1];   // (4096,1024)
    const float* b_in   = (const float*)d_in[2];   // (4096,)
    const float* conv_w = (const float*)d_in[3];   // (2048,1,3)
    const float* conv_b = (const float*)d_in[4];   // (2048,)
    const float* W_x    = (const float*)d_in[5];   // (96,2048)
    const float* W_dt   = (const float*)d_in[6];   // (2048,64)
    const float* b_dt   = (const float*)d_in[7];   // (2048,)
    const float* A_log  = (const float*)d_in[8];   // (2048,16)
    const float* W_out  = (const float*)d_in[9];   // (1024,2048)
    const float* b_out  = (const float*)d_in[10];  // (1024,)
    float* out = (float*)d_out;                    // (2,1024,1024) fp32

    // Workspace ~61 MB. delta aliases xc; ygb lives in its own slab.
    char* p = (char*)d_ws;
    auto alloc = [&](size_t bytes) { char* r = p; p += (bytes + 255) & ~(size_t)255; return r; };
    ushort_t* xbf    = (ushort_t*)alloc(2048ull * 1024 * 2);   // 4 MB
    ushort_t* winbf  = (ushort_t*)alloc(4096ull * 1024 * 2);   // 8 MB
    ushort_t* wxbf   = (ushort_t*)alloc(96ull * 2048 * 2);
    ushort_t* wdtbf  = (ushort_t*)alloc(2048ull * 64 * 2);
    ushort_t* woutbf = (ushort_t*)alloc(1024ull * 2048 * 2);   // 4 MB
    float*    xc     = (float*)alloc(2048ull * 2048 * 4);      // 16 MB (later: delta)
    float*    res    = (float*)alloc(2048ull * 2048 * 4);      // 16 MB
    ushort_t* ub     = (ushort_t*)alloc(2048ull * 2048 * 2);   // 8 MB
    float*    xpp    = (float*)alloc(4ull * 2048 * 96 * 4);    // 3 MB (split-K=4)
    float*    xp     = (float*)alloc(2048ull * 96 * 4);
    ushort_t* dltb   = (ushort_t*)alloc(2048ull * 64 * 2);
    ushort_t* ygb    = (ushort_t*)alloc(2048ull * 2048 * 2);   // 8 MB
    float*    delta  = xc;                                     // alias

    // 0. round x + weights to bf16
    cvt5<<<8512, 256, 0, stream>>>(x, W_in, W_x, W_dt, W_out,
                                   xbf, winbf, wxbf, wdtbf, woutbf);

    // 1. in_proj: xr = x @ W_in^T + b_in -> xc | res (fp32)
    gemm_bt<128, 128, 64, 2, 2, EPI_SPLIT><<<dim3(16, 32), 256, 0, stream>>>(
        xbf, 1024, winbf, 1024, xc, res, b_in, 4096, 1024);

    // 2. depthwise causal conv + silu -> ub (bf16)
    conv_silu<<<4096, 256, 0, stream>>>(xc, conv_w, conv_b, ub);

    // 3. x_proj: xp = u @ W_x^T (split-K=4, fp32 partials)
    gemm_bt<64, 96, 64, 4, 1, EPI_PARTIAL><<<dim3(32, 1, 4), 256, 0, stream>>>(
        ub, 2048, wxbf, 2048, xpp, nullptr, nullptr, 96, 512);

    // 4. reduce partials -> xp fp32, dlt bf16
    xp_reduce<<<768, 256, 0, stream>>>(xpp, xp, dltb);

    // 5. dt_proj: delta = softplus(dlt @ W_dt^T + b_dt) (fp32, overwrites xc)
    gemm_bt<128, 128, 64, 2, 2, EPI_SOFTPLUS><<<dim3(16, 16), 256, 0, stream>>>(
        dltb, 64, wdtbf, 64, delta, nullptr, b_dt, 2048, 64);

    // 6. chunked scan + silu(res) gating -> ygb (bf16)
    scan_kernel<<<dim3(128, 4, 2), 256, 0, stream>>>(delta, ub, xp, A_log, res, ygb);

    // 7. out_proj: out = yg @ W_out^T + b_out (fp32 out)
    gemm_bt<128, 64, 64, 2, 2, EPI_OUT><<<dim3(16, 16), 256, 0, stream>>>(
        ygb, 2048, woutbf, 2048, out, nullptr, b_out, 1024, 2048);
}

// Round 6
// 319.201 us; speedup vs baseline: 2.5311x; 1.3273x over previous
//
#include <hip/hip_runtime.h>
#include <stdint.h>
#include <stddef.h>

typedef __attribute__((ext_vector_type(8))) short short8;
typedef __attribute__((ext_vector_type(4))) float floatx4;
typedef unsigned short ushort_t;

__device__ __forceinline__ ushort_t f2bf(float f) {
    union { float f; uint32_t u; } v; v.f = f;
    return (ushort_t)((v.u + 0x7fffu + ((v.u >> 16) & 1u)) >> 16);
}
__device__ __forceinline__ float bf2f(ushort_t u) {
    union { uint32_t u; float f; } v; v.u = ((uint32_t)u) << 16; return v.f;
}

enum { EPI_SPLIT = 0, EPI_SOFTPLUS = 1, EPI_OUT = 2, EPI_PARTIAL = 3 };

// Convert x + 4 weights fp32 -> bf16 in one launch.
// float4 boundaries: x 524288 | W_in 1048576 | W_x 49152 | W_dt 32768 | W_out 524288
__global__ __launch_bounds__(256)
void cvt5(const float* __restrict__ x, const float* __restrict__ win,
          const float* __restrict__ wx, const float* __restrict__ wdt,
          const float* __restrict__ wout,
          ushort_t* __restrict__ xb, ushort_t* __restrict__ winb,
          ushort_t* __restrict__ wxb, ushort_t* __restrict__ wdtb,
          ushort_t* __restrict__ woutb)
{
    int g = blockIdx.x * 256 + threadIdx.x;   // < 2179072 exactly
    const float* s; ushort_t* d; int off;
    if      (g < 524288)  { s = x;    d = xb;    off = g; }
    else if (g < 1572864) { s = win;  d = winb;  off = g - 524288; }
    else if (g < 1622016) { s = wx;   d = wxb;   off = g - 1572864; }
    else if (g < 1654784) { s = wdt;  d = wdtb;  off = g - 1622016; }
    else                  { s = wout; d = woutb; off = g - 1654784; }
    float4 v = reinterpret_cast<const float4*>(s)[off];
    union { ushort_t u[4]; uint2 q; } o;
    o.u[0] = f2bf(v.x); o.u[1] = f2bf(v.y); o.u[2] = f2bf(v.z); o.u[3] = f2bf(v.w);
    *reinterpret_cast<uint2*>(d + (size_t)off * 4) = o.q;
}

// C[m,n] = sum_k A[m,k] * B[n,k]  (bf16 operands, fp32 accum, fp32 outputs)
template<int BM, int BN, int BK, int WR, int WC, int EPI>
__global__ __launch_bounds__(256)
void gemm_bt(const ushort_t* __restrict__ A, int lda,
             const ushort_t* __restrict__ Bw, int ldb,
             float* __restrict__ out0, float* __restrict__ out1,
             const float* __restrict__ bias,
             int N, int kchunk)
{
    constexpr int TM = BM / WR / 16;
    constexpr int TN = BN / WC / 16;
    static_assert(BM % (WR * 16) == 0 && BN % (WC * 16) == 0, "tile");
    static_assert((BM * BK) % 2048 == 0 && (BN * BK) % 2048 == 0, "stage");

    __shared__ __align__(16) short As[BM * BK];
    __shared__ __align__(16) short Bs[BN * BK];

    const int tid  = threadIdx.x;
    const int m0   = blockIdx.x * BM;
    const int n0   = blockIdx.y * BN;
    const int ks   = blockIdx.z;
    const int kbeg = ks * kchunk;

    const int w    = tid >> 6;
    const int lane = tid & 63;
    const int quad = lane >> 4;
    const int l16  = lane & 15;
    const int wr   = w / WC, wc = w % WC;
    const int wm   = wr * (BM / WR);
    const int wn   = wc * (BN / WC);

    floatx4 acc[TM][TN];
#pragma unroll
    for (int i = 0; i < TM; i++)
#pragma unroll
        for (int j = 0; j < TN; j++) acc[i][j] = (floatx4){0.f, 0.f, 0.f, 0.f};

    constexpr int nA = BM * BK / 2048;
    constexpr int nB = BN * BK / 2048;
    constexpr int CPR = BK / 8;

    for (int kb = kbeg; kb < kbeg + kchunk; kb += BK) {
        __syncthreads();
#pragma unroll
        for (int i = 0; i < nA; i++) {
            int c = i * 256 + tid;
            int r = c / CPR, kc = (c % CPR) * 8;
            short8 v = *reinterpret_cast<const short8*>(A + (size_t)(m0 + r) * lda + kb + kc);
            *reinterpret_cast<short8*>(&As[r * BK + kc]) = v;
        }
#pragma unroll
        for (int i = 0; i < nB; i++) {
            int c = i * 256 + tid;
            int r = c / CPR, kc = (c % CPR) * 8;
            short8 v = *reinterpret_cast<const short8*>(Bw + (size_t)(n0 + r) * ldb + kb + kc);
            *reinterpret_cast<short8*>(&Bs[r * BK + kc]) = v;
        }
        __syncthreads();
#pragma unroll
        for (int kk = 0; kk < BK / 32; kk++) {
            short8 af[TM], bfr[TN];
#pragma unroll
            for (int t = 0; t < TM; t++)
                af[t] = *reinterpret_cast<const short8*>(&As[(wm + t * 16 + l16) * BK + kk * 32 + quad * 8]);
#pragma unroll
            for (int u2 = 0; u2 < TN; u2++)
                bfr[u2] = *reinterpret_cast<const short8*>(&Bs[(wn + u2 * 16 + l16) * BK + kk * 32 + quad * 8]);
#pragma unroll
            for (int t = 0; t < TM; t++)
#pragma unroll
                for (int u2 = 0; u2 < TN; u2++)
                    acc[t][u2] = __builtin_amdgcn_mfma_f32_16x16x32_bf16(af[t], bfr[u2], acc[t][u2], 0, 0, 0);
        }
    }

#pragma unroll
    for (int t = 0; t < TM; t++) {
#pragma unroll
        for (int u2 = 0; u2 < TN; u2++) {
#pragma unroll
            for (int r = 0; r < 4; r++) {
                int row = m0 + wm + t * 16 + quad * 4 + r;
                int col = n0 + wn + u2 * 16 + l16;
                float val = acc[t][u2][r];
                if (EPI == EPI_SPLIT) {
                    val += bias[col];
                    if (col < 2048) out0[(size_t)row * 2048 + col] = val;
                    else            out1[(size_t)row * 2048 + col - 2048] = val;
                } else if (EPI == EPI_SOFTPLUS) {
                    val += bias[col];
                    float sp = (val > 15.f) ? val : log1pf(__expf(val));
                    out0[(size_t)row * N + col] = sp;
                } else if (EPI == EPI_OUT) {
                    val += bias[col];
                    out0[(size_t)row * N + col] = val;
                } else { // EPI_PARTIAL: split-K partials [ks][m][96]
                    out0[((size_t)ks * 2048 + row) * 96 + col] = val;
                }
            }
        }
    }
}

// depthwise causal conv (k=3) + silu. fp32 in, bf16 out.
__global__ __launch_bounds__(256)
void conv_silu(const float* __restrict__ xc, const float* __restrict__ cw,
               const float* __restrict__ cb, ushort_t* __restrict__ ub)
{
    int id = blockIdx.x * 256 + threadIdx.x;   // 2048 * 512
    int m  = id >> 9;
    int d4 = (id & 511) * 4;
    int l  = m & 1023;

    const float4 zero = make_float4(0.f, 0.f, 0.f, 0.f);
    float4 a = *reinterpret_cast<const float4*>(xc + (size_t)m * 2048 + d4);
    float4 b = (l >= 1) ? *reinterpret_cast<const float4*>(xc + (size_t)(m - 1) * 2048 + d4) : zero;
    float4 c = (l >= 2) ? *reinterpret_cast<const float4*>(xc + (size_t)(m - 2) * 2048 + d4) : zero;

    float av[4] = {a.x, a.y, a.z, a.w};
    float bv[4] = {b.x, b.y, b.z, b.w};
    float cv[4] = {c.x, c.y, c.z, c.w};
    union { ushort_t u[4]; uint2 q; } o;
#pragma unroll
    for (int j = 0; j < 4; j++) {
        int d = d4 + j;
        float v = cb[d] + cw[d * 3 + 0] * cv[j] + cw[d * 3 + 1] * bv[j] + cw[d * 3 + 2] * av[j];
        o.u[j] = f2bf(v / (1.f + __expf(-v)));
    }
    *reinterpret_cast<uint2*>(ub + (size_t)m * 2048 + d4) = o.q;
}

// reduce split-K=4 partials -> xp fp32 (2048 x 96) and dlt bf16 (2048 x 64)
__global__ __launch_bounds__(256)
void xp_reduce(const float* __restrict__ part, float* __restrict__ xp, ushort_t* __restrict__ dltb)
{
    int e = blockIdx.x * 256 + threadIdx.x;    // < 2048*96 exactly
    float s = 0.f;
#pragma unroll
    for (int ks = 0; ks < 4; ks++) s += part[(size_t)ks * 2048 * 96 + e];
    xp[e] = s;
    int n = e % 96, m = e / 96;
    if (n < 64) dltb[(size_t)m * 64 + n] = f2bf(s);
}

// Chunked selective scan, wave-parallel over time.
// Block = 256 thr = 4 waves; block covers one 256-token chunk x 32 channels.
// lane&31 = channel d, lane>>5 = state-half h (8 of 16 states per thread).
// Wave w owns local timesteps [64w, 64w+64).
// Phase 1: local affine scan from s=0 -> segment output q, plus sum(delta).
//   (segment decay prod_t exp(dv*A) == exp(A * sum dv) -- one scalar per (w,d).)
// Phase 2: carry s_in(w) = sum_{v<w} exp(A*cum_S) * q_v  (cheap, log-free).
// Phase 3: replay local timesteps from s_in, emit y = sum_n s_n*C, gate, store.
__global__ __launch_bounds__(256)
void scan_kernel(const float* __restrict__ delta, const ushort_t* __restrict__ ub,
                 const float* __restrict__ xp, const float* __restrict__ A_log,
                 const float* __restrict__ res, ushort_t* __restrict__ ygb)
{
    __shared__ __align__(16) float Bsh[256 * 16];
    __shared__ __align__(16) float Csh[256 * 16];
    __shared__ float sQ[4][32][17];   // +1 pad: breaks 16-stride bank aliasing
    __shared__ float sS[4][32];

    const int tid  = threadIdx.x;
    const int w    = tid >> 6;
    const int lane = tid & 63;
    const int dl   = lane & 31;
    const int h    = lane >> 5;               // state half: n in [8h, 8h+8)
    const int d    = blockIdx.x * 32 + dl;
    const int c    = blockIdx.y;              // 0..7 = (batch, chunk)
    const int mbase = (c >> 2) * 1024 + (c & 3) * 256;

    {   // stage B (xp cols 64..79) and C (cols 80..95) for all 256 tokens
        const float4* rp4 = reinterpret_cast<const float4*>(xp + (size_t)(mbase + tid) * 96 + 64);
        float4* bd = reinterpret_cast<float4*>(&Bsh[tid * 16]);
        float4* cd = reinterpret_cast<float4*>(&Csh[tid * 16]);
        bd[0] = rp4[0]; bd[1] = rp4[1]; bd[2] = rp4[2]; bd[3] = rp4[3];
        cd[0] = rp4[4]; cd[1] = rp4[5]; cd[2] = rp4[6]; cd[3] = rp4[7];
    }

    float Av[8];
    {
        const float4* ap = reinterpret_cast<const float4*>(A_log + (size_t)d * 16 + h * 8);
        float4 a0 = ap[0], a1 = ap[1];
        Av[0] = -__expf(a0.x); Av[1] = -__expf(a0.y); Av[2] = -__expf(a0.z); Av[3] = -__expf(a0.w);
        Av[4] = -__expf(a1.x); Av[5] = -__expf(a1.y); Av[6] = -__expf(a1.z); Av[7] = -__expf(a1.w);
    }

    float s[8];
#pragma unroll
    for (int n = 0; n < 8; n++) s[n] = 0.f;
    float sumdv = 0.f;
    const int t0 = w * 64;
    __syncthreads();

    // ---- phase 1: local segment scan (s_in = 0) ----
#pragma unroll 4
    for (int tt = 0; tt < 64; tt++) {
        int t = t0 + tt;
        size_t idx = (size_t)(mbase + t) * 2048 + d;
        float dvv = delta[idx];
        float uv  = bf2f(ub[idx]);
        float dvu = dvv * uv;
        sumdv += dvv;
        const float* Brow = &Bsh[t * 16 + h * 8];
#pragma unroll
        for (int n = 0; n < 8; n++) {
            float dA = __expf(dvv * Av[n]);
            s[n] = fmaf(dA, s[n], dvu * Brow[n]);
        }
    }
#pragma unroll
    for (int n = 0; n < 8; n++) sQ[w][dl][h * 8 + n] = s[n];
    if (h == 0) sS[w][dl] = sumdv;
    __syncthreads();

    // ---- phase 2: compose carry from lower waves ----
    {
        float sin_[8];
#pragma unroll
        for (int n = 0; n < 8; n++) sin_[n] = 0.f;
        float cum = 0.f;   // sum of S_j for j in (v, w)
        for (int v = w - 1; v >= 0; v--) {
#pragma unroll
            for (int n = 0; n < 8; n++)
                sin_[n] += __expf(Av[n] * cum) * sQ[v][dl][h * 8 + n];
            cum += sS[v][dl];
        }
#pragma unroll
        for (int n = 0; n < 8; n++) s[n] = sin_[n];
    }

    // ---- phase 3: replay with carry, emit gated y ----
#pragma unroll 2
    for (int tt = 0; tt < 64; tt++) {
        int t = t0 + tt;
        size_t idx = (size_t)(mbase + t) * 2048 + d;
        float dvv = delta[idx];
        float uv  = bf2f(ub[idx]);
        float dvu = dvv * uv;
        const float* Brow = &Bsh[t * 16 + h * 8];
        const float* Crow = &Csh[t * 16 + h * 8];
        float y = 0.f;
#pragma unroll
        for (int n = 0; n < 8; n++) {
            float dA = __expf(dvv * Av[n]);
            s[n] = fmaf(dA, s[n], dvu * Brow[n]);
            y = fmaf(s[n], Crow[n], y);
        }
        y += __shfl_xor(y, 32);
        if (h == 0) {
            float r = res[idx];
            float sr = r / (1.f + __expf(-r));
            ygb[idx] = f2bf(y * sr);
        }
    }
}

extern "C" void kernel_launch(void* const* d_in, const int* in_sizes, int n_in,
                              void* d_out, int out_size, void* d_ws, size_t ws_size,
                              hipStream_t stream)
{
    const float* x      = (const float*)d_in[0];   // (2,1024,1024) fp32
    const float* W_in   = (const float*)d_in[1];   // (4096,1024)
    const float* b_in   = (const float*)d_in[2];   // (4096,)
    const float* conv_w = (const float*)d_in[3];   // (2048,1,3)
    const float* conv_b = (const float*)d_in[4];   // (2048,)
    const float* W_x    = (const float*)d_in[5];   // (96,2048)
    const float* W_dt   = (const float*)d_in[6];   // (2048,64)
    const float* b_dt   = (const float*)d_in[7];   // (2048,)
    const float* A_log  = (const float*)d_in[8];   // (2048,16)
    const float* W_out  = (const float*)d_in[9];   // (1024,2048)
    const float* b_out  = (const float*)d_in[10];  // (1024,)
    float* out = (float*)d_out;                    // (2,1024,1024) fp32

    // Workspace ~61 MB. delta aliases xc (dead after conv).
    char* p = (char*)d_ws;
    auto alloc = [&](size_t bytes) { char* r = p; p += (bytes + 255) & ~(size_t)255; return r; };
    ushort_t* xbf    = (ushort_t*)alloc(2048ull * 1024 * 2);   // 4 MB
    ushort_t* winbf  = (ushort_t*)alloc(4096ull * 1024 * 2);   // 8 MB
    ushort_t* wxbf   = (ushort_t*)alloc(96ull * 2048 * 2);
    ushort_t* wdtbf  = (ushort_t*)alloc(2048ull * 64 * 2);
    ushort_t* woutbf = (ushort_t*)alloc(1024ull * 2048 * 2);   // 4 MB
    float*    xc     = (float*)alloc(2048ull * 2048 * 4);      // 16 MB (later: delta)
    float*    res    = (float*)alloc(2048ull * 2048 * 4);      // 16 MB
    ushort_t* ub     = (ushort_t*)alloc(2048ull * 2048 * 2);   // 8 MB
    float*    xpp    = (float*)alloc(4ull * 2048 * 96 * 4);    // 3 MB (split-K=4)
    float*    xp     = (float*)alloc(2048ull * 96 * 4);
    ushort_t* dltb   = (ushort_t*)alloc(2048ull * 64 * 2);
    ushort_t* ygb    = (ushort_t*)alloc(2048ull * 2048 * 2);   // 8 MB
    float*    delta  = xc;                                     // alias

    // 0. round x + weights to bf16
    cvt5<<<8512, 256, 0, stream>>>(x, W_in, W_x, W_dt, W_out,
                                   xbf, winbf, wxbf, wdtbf, woutbf);

    // 1. in_proj: xr = x @ W_in^T + b_in -> xc | res (fp32)
    gemm_bt<128, 128, 64, 2, 2, EPI_SPLIT><<<dim3(16, 32), 256, 0, stream>>>(
        xbf, 1024, winbf, 1024, xc, res, b_in, 4096, 1024);

    // 2. depthwise causal conv + silu -> ub (bf16)
    conv_silu<<<4096, 256, 0, stream>>>(xc, conv_w, conv_b, ub);

    // 3. x_proj: xp = u @ W_x^T (split-K=4, fp32 partials)
    gemm_bt<64, 96, 64, 4, 1, EPI_PARTIAL><<<dim3(32, 1, 4), 256, 0, stream>>>(
        ub, 2048, wxbf, 2048, xpp, nullptr, nullptr, 96, 512);

    // 4. reduce partials -> xp fp32, dlt bf16
    xp_reduce<<<768, 256, 0, stream>>>(xpp, xp, dltb);

    // 5. dt_proj: delta = softplus(dlt @ W_dt^T + b_dt) (fp32, overwrites xc)
    gemm_bt<128, 128, 64, 2, 2, EPI_SOFTPLUS><<<dim3(16, 16), 256, 0, stream>>>(
        dltb, 64, wdtbf, 64, delta, nullptr, b_dt, 2048, 64);

    // 6. wave-parallel chunked scan + silu(res) gating -> ygb (bf16)
    scan_kernel<<<dim3(64, 8), 256, 0, stream>>>(delta, ub, xp, A_log, res, ygb);

    // 7. out_proj: out = yg @ W_out^T + b_out (fp32 out)
    gemm_bt<128, 64, 64, 2, 2, EPI_OUT><<<dim3(16, 16), 256, 0, stream>>>(
        ygb, 2048, woutbf, 2048, out, nullptr, b_out, 1024, 2048);
}

// Round 7
// 259.974 us; speedup vs baseline: 3.1077x; 1.2278x over previous
//
#include <hip/hip_runtime.h>
#include <stdint.h>
#include <stddef.h>

typedef __attribute__((ext_vector_type(8))) short short8;
typedef __attribute__((ext_vector_type(4))) float floatx4;
typedef unsigned short ushort_t;

__device__ __forceinline__ ushort_t f2bf(float f) {
    union { float f; uint32_t u; } v; v.f = f;
    return (ushort_t)((v.u + 0x7fffu + ((v.u >> 16) & 1u)) >> 16);
}
__device__ __forceinline__ float bf2f(ushort_t u) {
    union { uint32_t u; float f; } v; v.u = ((uint32_t)u) << 16; return v.f;
}

// async global->LDS 16B staging (m97 technique). LDS dest must be
// wave-uniform-base + lane*16 -- our staging index is tid-linear, so it is.
__device__ __forceinline__ void load16_lds(const ushort_t* g, short* l) {
    __builtin_amdgcn_global_load_lds((const __attribute__((address_space(1))) void*)g,
                                     (__attribute__((address_space(3))) void*)l, 16, 0, 0);
}

enum { EPI_SPLIT = 0, EPI_SOFTPLUS = 1, EPI_OUT = 2, EPI_PARTIAL = 3 };

// Convert x + 4 weights fp32 -> bf16 in one launch.
// float4 boundaries: x 524288 | W_in 1048576 | W_x 49152 | W_dt 32768 | W_out 524288
__global__ __launch_bounds__(256)
void cvt5(const float* __restrict__ x, const float* __restrict__ win,
          const float* __restrict__ wx, const float* __restrict__ wdt,
          const float* __restrict__ wout,
          ushort_t* __restrict__ xb, ushort_t* __restrict__ winb,
          ushort_t* __restrict__ wxb, ushort_t* __restrict__ wdtb,
          ushort_t* __restrict__ woutb)
{
    int g = blockIdx.x * 256 + threadIdx.x;   // < 2179072 exactly
    const float* s; ushort_t* d; int off;
    if      (g < 524288)  { s = x;    d = xb;    off = g; }
    else if (g < 1572864) { s = win;  d = winb;  off = g - 524288; }
    else if (g < 1622016) { s = wx;   d = wxb;   off = g - 1572864; }
    else if (g < 1654784) { s = wdt;  d = wdtb;  off = g - 1622016; }
    else                  { s = wout; d = woutb; off = g - 1654784; }
    float4 v = reinterpret_cast<const float4*>(s)[off];
    union { ushort_t u[4]; uint2 q; } o;
    o.u[0] = f2bf(v.x); o.u[1] = f2bf(v.y); o.u[2] = f2bf(v.z); o.u[3] = f2bf(v.w);
    *reinterpret_cast<uint2*>(d + (size_t)off * 4) = o.q;
}

// C[m,n] = sum_k A[m,k] * B[n,k]  (bf16 operands, fp32 accum, fp32 outputs)
template<int BM, int BN, int BK, int WR, int WC, int EPI>
__global__ __launch_bounds__(256)
void gemm_bt(const ushort_t* __restrict__ A, int lda,
             const ushort_t* __restrict__ Bw, int ldb,
             float* __restrict__ out0, float* __restrict__ out1,
             const float* __restrict__ bias,
             int N, int kchunk)
{
    constexpr int TM = BM / WR / 16;
    constexpr int TN = BN / WC / 16;
    static_assert(BM % (WR * 16) == 0 && BN % (WC * 16) == 0, "tile");
    static_assert((BM * BK) % 2048 == 0 && (BN * BK) % 2048 == 0, "stage");

    __shared__ __align__(16) short As[BM * BK];
    __shared__ __align__(16) short Bs[BN * BK];

    const int tid  = threadIdx.x;
    const int m0   = blockIdx.x * BM;
    const int n0   = blockIdx.y * BN;
    const int ks   = blockIdx.z;
    const int kbeg = ks * kchunk;

    const int w    = tid >> 6;
    const int lane = tid & 63;
    const int quad = lane >> 4;
    const int l16  = lane & 15;
    const int wr   = w / WC, wc = w % WC;
    const int wm   = wr * (BM / WR);
    const int wn   = wc * (BN / WC);

    floatx4 acc[TM][TN];
#pragma unroll
    for (int i = 0; i < TM; i++)
#pragma unroll
        for (int j = 0; j < TN; j++) acc[i][j] = (floatx4){0.f, 0.f, 0.f, 0.f};

    constexpr int nA = BM * BK / 2048;
    constexpr int nB = BN * BK / 2048;
    constexpr int CPR = BK / 8;

    for (int kb = kbeg; kb < kbeg + kchunk; kb += BK) {
        __syncthreads();
#pragma unroll
        for (int i = 0; i < nA; i++) {
            int c = i * 256 + tid;
            int r = c / CPR, kc = (c % CPR) * 8;
            load16_lds(A + (size_t)(m0 + r) * lda + kb + kc, &As[r * BK + kc]);
        }
#pragma unroll
        for (int i = 0; i < nB; i++) {
            int c = i * 256 + tid;
            int r = c / CPR, kc = (c % CPR) * 8;
            load16_lds(Bw + (size_t)(n0 + r) * ldb + kb + kc, &Bs[r * BK + kc]);
        }
        __syncthreads();
#pragma unroll
        for (int kk = 0; kk < BK / 32; kk++) {
            short8 af[TM], bfr[TN];
#pragma unroll
            for (int t = 0; t < TM; t++)
                af[t] = *reinterpret_cast<const short8*>(&As[(wm + t * 16 + l16) * BK + kk * 32 + quad * 8]);
#pragma unroll
            for (int u2 = 0; u2 < TN; u2++)
                bfr[u2] = *reinterpret_cast<const short8*>(&Bs[(wn + u2 * 16 + l16) * BK + kk * 32 + quad * 8]);
#pragma unroll
            for (int t = 0; t < TM; t++)
#pragma unroll
                for (int u2 = 0; u2 < TN; u2++)
                    acc[t][u2] = __builtin_amdgcn_mfma_f32_16x16x32_bf16(af[t], bfr[u2], acc[t][u2], 0, 0, 0);
        }
    }

#pragma unroll
    for (int t = 0; t < TM; t++) {
#pragma unroll
        for (int u2 = 0; u2 < TN; u2++) {
#pragma unroll
            for (int r = 0; r < 4; r++) {
                int row = m0 + wm + t * 16 + quad * 4 + r;
                int col = n0 + wn + u2 * 16 + l16;
                float val = acc[t][u2][r];
                if (EPI == EPI_SPLIT) {
                    val += bias[col];
                    if (col < 2048) out0[(size_t)row * 2048 + col] = val;
                    else            out1[(size_t)row * 2048 + col - 2048] = val;
                } else if (EPI == EPI_SOFTPLUS) {
                    val += bias[col];
                    // fast stable softplus: max(v,0) + log(1+exp(-|v|)); tiny
                    // inline code (ocml log1pf blew up epilogue code size).
                    float sp = fmaxf(val, 0.f) + __logf(1.f + __expf(-fabsf(val)));
                    out0[(size_t)row * N + col] = sp;
                } else if (EPI == EPI_OUT) {
                    val += bias[col];
                    out0[(size_t)row * N + col] = val;
                } else { // EPI_PARTIAL: split-K partials [ks][m][96]
                    out0[((size_t)ks * 2048 + row) * 96 + col] = val;
                }
            }
        }
    }
}

// depthwise causal conv (k=3) + silu. fp32 in, bf16 out.
__global__ __launch_bounds__(256)
void conv_silu(const float* __restrict__ xc, const float* __restrict__ cw,
               const float* __restrict__ cb, ushort_t* __restrict__ ub)
{
    int id = blockIdx.x * 256 + threadIdx.x;   // 2048 * 512
    int m  = id >> 9;
    int d4 = (id & 511) * 4;
    int l  = m & 1023;

    const float4 zero = make_float4(0.f, 0.f, 0.f, 0.f);
    float4 a = *reinterpret_cast<const float4*>(xc + (size_t)m * 2048 + d4);
    float4 b = (l >= 1) ? *reinterpret_cast<const float4*>(xc + (size_t)(m - 1) * 2048 + d4) : zero;
    float4 c = (l >= 2) ? *reinterpret_cast<const float4*>(xc + (size_t)(m - 2) * 2048 + d4) : zero;

    float av[4] = {a.x, a.y, a.z, a.w};
    float bv[4] = {b.x, b.y, b.z, b.w};
    float cv[4] = {c.x, c.y, c.z, c.w};
    union { ushort_t u[4]; uint2 q; } o;
#pragma unroll
    for (int j = 0; j < 4; j++) {
        int d = d4 + j;
        float v = cb[d] + cw[d * 3 + 0] * cv[j] + cw[d * 3 + 1] * bv[j] + cw[d * 3 + 2] * av[j];
        o.u[j] = f2bf(v / (1.f + __expf(-v)));
    }
    *reinterpret_cast<uint2*>(ub + (size_t)m * 2048 + d4) = o.q;
}

// reduce split-K=4 partials -> xp fp32 (2048 x 96) and dlt bf16 (2048 x 64)
__global__ __launch_bounds__(256)
void xp_reduce(const float* __restrict__ part, float* __restrict__ xp, ushort_t* __restrict__ dltb)
{
    int e = blockIdx.x * 256 + threadIdx.x;    // < 2048*96 exactly
    float s = 0.f;
#pragma unroll
    for (int ks = 0; ks < 4; ks++) s += part[(size_t)ks * 2048 * 96 + e];
    xp[e] = s;
    int n = e % 96, m = e / 96;
    if (n < 64) dltb[(size_t)m * 64 + n] = f2bf(s);
}

// Chunked selective scan, wave-parallel over time (see r6 notes).
__global__ __launch_bounds__(256)
void scan_kernel(const float* __restrict__ delta, const ushort_t* __restrict__ ub,
                 const float* __restrict__ xp, const float* __restrict__ A_log,
                 const float* __restrict__ res, ushort_t* __restrict__ ygb)
{
    __shared__ __align__(16) float Bsh[256 * 16];
    __shared__ __align__(16) float Csh[256 * 16];
    __shared__ float sQ[4][32][17];
    __shared__ float sS[4][32];

    const int tid  = threadIdx.x;
    const int w    = tid >> 6;
    const int lane = tid & 63;
    const int dl   = lane & 31;
    const int h    = lane >> 5;
    const int d    = blockIdx.x * 32 + dl;
    const int c    = blockIdx.y;
    const int mbase = (c >> 2) * 1024 + (c & 3) * 256;

    {
        const float4* rp4 = reinterpret_cast<const float4*>(xp + (size_t)(mbase + tid) * 96 + 64);
        float4* bd = reinterpret_cast<float4*>(&Bsh[tid * 16]);
        float4* cd = reinterpret_cast<float4*>(&Csh[tid * 16]);
        bd[0] = rp4[0]; bd[1] = rp4[1]; bd[2] = rp4[2]; bd[3] = rp4[3];
        cd[0] = rp4[4]; cd[1] = rp4[5]; cd[2] = rp4[6]; cd[3] = rp4[7];
    }

    float Av[8];
    {
        const float4* ap = reinterpret_cast<const float4*>(A_log + (size_t)d * 16 + h * 8);
        float4 a0 = ap[0], a1 = ap[1];
        Av[0] = -__expf(a0.x); Av[1] = -__expf(a0.y); Av[2] = -__expf(a0.z); Av[3] = -__expf(a0.w);
        Av[4] = -__expf(a1.x); Av[5] = -__expf(a1.y); Av[6] = -__expf(a1.z); Av[7] = -__expf(a1.w);
    }

    float s[8];
#pragma unroll
    for (int n = 0; n < 8; n++) s[n] = 0.f;
    float sumdv = 0.f;
    const int t0 = w * 64;
    __syncthreads();

    // phase 1: local segment scan (s_in = 0)
#pragma unroll 4
    for (int tt = 0; tt < 64; tt++) {
        int t = t0 + tt;
        size_t idx = (size_t)(mbase + t) * 2048 + d;
        float dvv = delta[idx];
        float uv  = bf2f(ub[idx]);
        float dvu = dvv * uv;
        sumdv += dvv;
        const float* Brow = &Bsh[t * 16 + h * 8];
#pragma unroll
        for (int n = 0; n < 8; n++) {
            float dA = __expf(dvv * Av[n]);
            s[n] = fmaf(dA, s[n], dvu * Brow[n]);
        }
    }
#pragma unroll
    for (int n = 0; n < 8; n++) sQ[w][dl][h * 8 + n] = s[n];
    if (h == 0) sS[w][dl] = sumdv;
    __syncthreads();

    // phase 2: compose carry from lower waves
    {
        float sin_[8];
#pragma unroll
        for (int n = 0; n < 8; n++) sin_[n] = 0.f;
        float cum = 0.f;
        for (int v = w - 1; v >= 0; v--) {
#pragma unroll
            for (int n = 0; n < 8; n++)
                sin_[n] += __expf(Av[n] * cum) * sQ[v][dl][h * 8 + n];
            cum += sS[v][dl];
        }
#pragma unroll
        for (int n = 0; n < 8; n++) s[n] = sin_[n];
    }

    // phase 3: replay with carry, emit gated y
#pragma unroll 2
    for (int tt = 0; tt < 64; tt++) {
        int t = t0 + tt;
        size_t idx = (size_t)(mbase + t) * 2048 + d;
        float dvv = delta[idx];
        float uv  = bf2f(ub[idx]);
        float dvu = dvv * uv;
        const float* Brow = &Bsh[t * 16 + h * 8];
        const float* Crow = &Csh[t * 16 + h * 8];
        float y = 0.f;
#pragma unroll
        for (int n = 0; n < 8; n++) {
            float dA = __expf(dvv * Av[n]);
            s[n] = fmaf(dA, s[n], dvu * Brow[n]);
            y = fmaf(s[n], Crow[n], y);
        }
        y += __shfl_xor(y, 32);
        if (h == 0) {
            float r = res[idx];
            float sr = r / (1.f + __expf(-r));
            ygb[idx] = f2bf(y * sr);
        }
    }
}

extern "C" void kernel_launch(void* const* d_in, const int* in_sizes, int n_in,
                              void* d_out, int out_size, void* d_ws, size_t ws_size,
                              hipStream_t stream)
{
    const float* x      = (const float*)d_in[0];   // (2,1024,1024) fp32
    const float* W_in   = (const float*)d_in[1];   // (4096,1024)
    const float* b_in   = (const float*)d_in[2];   // (4096,)
    const float* conv_w = (const float*)d_in[3];   // (2048,1,3)
    const float* conv_b = (const float*)d_in[4];   // (2048,)
    const float* W_x    = (const float*)d_in[5];   // (96,2048)
    const float* W_dt   = (const float*)d_in[6];   // (2048,64)
    const float* b_dt   = (const float*)d_in[7];   // (2048,)
    const float* A_log  = (const float*)d_in[8];   // (2048,16)
    const float* W_out  = (const float*)d_in[9];   // (1024,2048)
    const float* b_out  = (const float*)d_in[10];  // (1024,)
    float* out = (float*)d_out;                    // (2,1024,1024) fp32

    // Workspace ~61 MB. delta aliases xc (dead after conv).
    char* p = (char*)d_ws;
    auto alloc = [&](size_t bytes) { char* r = p; p += (bytes + 255) & ~(size_t)255; return r; };
    ushort_t* xbf    = (ushort_t*)alloc(2048ull * 1024 * 2);   // 4 MB
    ushort_t* winbf  = (ushort_t*)alloc(4096ull * 1024 * 2);   // 8 MB
    ushort_t* wxbf   = (ushort_t*)alloc(96ull * 2048 * 2);
    ushort_t* wdtbf  = (ushort_t*)alloc(2048ull * 64 * 2);
    ushort_t* woutbf = (ushort_t*)alloc(1024ull * 2048 * 2);   // 4 MB
    float*    xc     = (float*)alloc(2048ull * 2048 * 4);      // 16 MB (later: delta)
    float*    res    = (float*)alloc(2048ull * 2048 * 4);      // 16 MB
    ushort_t* ub     = (ushort_t*)alloc(2048ull * 2048 * 2);   // 8 MB
    float*    xpp    = (float*)alloc(4ull * 2048 * 96 * 4);    // 3 MB (split-K=4)
    float*    xp     = (float*)alloc(2048ull * 96 * 4);
    ushort_t* dltb   = (ushort_t*)alloc(2048ull * 64 * 2);
    ushort_t* ygb    = (ushort_t*)alloc(2048ull * 2048 * 2);   // 8 MB
    float*    delta  = xc;                                     // alias

    // 0. round x + weights to bf16
    cvt5<<<8512, 256, 0, stream>>>(x, W_in, W_x, W_dt, W_out,
                                   xbf, winbf, wxbf, wdtbf, woutbf);

    // 1. in_proj: xr = x @ W_in^T + b_in -> xc | res (fp32)
    gemm_bt<128, 128, 64, 2, 2, EPI_SPLIT><<<dim3(16, 32), 256, 0, stream>>>(
        xbf, 1024, winbf, 1024, xc, res, b_in, 4096, 1024);

    // 2. depthwise causal conv + silu -> ub (bf16)
    conv_silu<<<4096, 256, 0, stream>>>(xc, conv_w, conv_b, ub);

    // 3. x_proj: xp = u @ W_x^T (split-K=4, fp32 partials)
    gemm_bt<64, 96, 64, 4, 1, EPI_PARTIAL><<<dim3(32, 1, 4), 256, 0, stream>>>(
        ub, 2048, wxbf, 2048, xpp, nullptr, nullptr, 96, 512);

    // 4. reduce partials -> xp fp32, dlt bf16
    xp_reduce<<<768, 256, 0, stream>>>(xpp, xp, dltb);

    // 5. dt_proj: delta = softplus(dlt @ W_dt^T + b_dt) (fp32, overwrites xc)
    //    64x64 tiles -> 1024 blocks (4/CU) for latency hiding; K=64 is tiny.
    gemm_bt<64, 64, 64, 2, 2, EPI_SOFTPLUS><<<dim3(32, 32), 256, 0, stream>>>(
        dltb, 64, wdtbf, 64, delta, nullptr, b_dt, 2048, 64);

    // 6. wave-parallel chunked scan + silu(res) gating -> ygb (bf16)
    scan_kernel<<<dim3(64, 8), 256, 0, stream>>>(delta, ub, xp, A_log, res, ygb);

    // 7. out_proj: out = yg @ W_out^T + b_out (fp32 out)
    gemm_bt<128, 64, 64, 2, 2, EPI_OUT><<<dim3(16, 16), 256, 0, stream>>>(
        ygb, 2048, woutbf, 2048, out, nullptr, b_out, 1024, 2048);
}

// Round 8
// 256.392 us; speedup vs baseline: 3.1512x; 1.0140x over previous
//
#include <hip/hip_runtime.h>
#include <stdint.h>
#include <stddef.h>

typedef __attribute__((ext_vector_type(8))) short short8;
typedef __attribute__((ext_vector_type(4))) float floatx4;
typedef unsigned short ushort_t;

__device__ __forceinline__ ushort_t f2bf(float f) {
    union { float f; uint32_t u; } v; v.f = f;
    return (ushort_t)((v.u + 0x7fffu + ((v.u >> 16) & 1u)) >> 16);
}
__device__ __forceinline__ float bf2f(ushort_t u) {
    union { uint32_t u; float f; } v; v.u = ((uint32_t)u) << 16; return v.f;
}

// async global->LDS 16B staging (m97). LDS dest = wave-uniform base + lane*16.
__device__ __forceinline__ void load16_lds(const ushort_t* g, short* l) {
    __builtin_amdgcn_global_load_lds((const __attribute__((address_space(1))) void*)g,
                                     (__attribute__((address_space(3))) void*)l, 16, 0, 0);
}

enum { EPI_SPLIT = 0, EPI_SOFTPLUS = 1, EPI_OUT = 2, EPI_PARTIAL = 3 };

// Convert x + 4 weights fp32 -> bf16 in one launch.
__global__ __launch_bounds__(256)
void cvt5(const float* __restrict__ x, const float* __restrict__ win,
          const float* __restrict__ wx, const float* __restrict__ wdt,
          const float* __restrict__ wout,
          ushort_t* __restrict__ xb, ushort_t* __restrict__ winb,
          ushort_t* __restrict__ wxb, ushort_t* __restrict__ wdtb,
          ushort_t* __restrict__ woutb)
{
    int g = blockIdx.x * 256 + threadIdx.x;   // < 2179072 exactly
    const float* s; ushort_t* d; int off;
    if      (g < 524288)  { s = x;    d = xb;    off = g; }
    else if (g < 1572864) { s = win;  d = winb;  off = g - 524288; }
    else if (g < 1622016) { s = wx;   d = wxb;   off = g - 1572864; }
    else if (g < 1654784) { s = wdt;  d = wdtb;  off = g - 1622016; }
    else                  { s = wout; d = woutb; off = g - 1654784; }
    float4 v = reinterpret_cast<const float4*>(s)[off];
    union { ushort_t u[4]; uint2 q; } o;
    o.u[0] = f2bf(v.x); o.u[1] = f2bf(v.y); o.u[2] = f2bf(v.z); o.u[3] = f2bf(v.w);
    *reinterpret_cast<uint2*>(d + (size_t)off * 4) = o.q;
}

// C[m,n] = sum_k A[m,k] * B[n,k]  (bf16 operands, fp32 accum)
template<int BM, int BN, int BK, int WR, int WC, int EPI>
__global__ __launch_bounds__(256)
void gemm_bt(const ushort_t* __restrict__ A, int lda,
             const ushort_t* __restrict__ Bw, int ldb,
             float* __restrict__ out0, float* __restrict__ out1,
             ushort_t* __restrict__ outb,
             const float* __restrict__ bias,
             int N, int kchunk)
{
    constexpr int TM = BM / WR / 16;
    constexpr int TN = BN / WC / 16;
    static_assert(BM % (WR * 16) == 0 && BN % (WC * 16) == 0, "tile");
    static_assert((BM * BK) % 2048 == 0 && (BN * BK) % 2048 == 0, "stage");

    __shared__ __align__(16) short As[BM * BK];
    __shared__ __align__(16) short Bs[BN * BK];

    const int tid  = threadIdx.x;
    const int m0   = blockIdx.x * BM;
    const int n0   = blockIdx.y * BN;
    const int ks   = blockIdx.z;
    const int kbeg = ks * kchunk;

    const int w    = tid >> 6;
    const int lane = tid & 63;
    const int quad = lane >> 4;
    const int l16  = lane & 15;
    const int wr   = w / WC, wc = w % WC;
    const int wm   = wr * (BM / WR);
    const int wn   = wc * (BN / WC);

    floatx4 acc[TM][TN];
#pragma unroll
    for (int i = 0; i < TM; i++)
#pragma unroll
        for (int j = 0; j < TN; j++) acc[i][j] = (floatx4){0.f, 0.f, 0.f, 0.f};

    constexpr int nA = BM * BK / 2048;
    constexpr int nB = BN * BK / 2048;
    constexpr int CPR = BK / 8;

    for (int kb = kbeg; kb < kbeg + kchunk; kb += BK) {
        __syncthreads();
#pragma unroll
        for (int i = 0; i < nA; i++) {
            int c = i * 256 + tid;
            int r = c / CPR, kc = (c % CPR) * 8;
            load16_lds(A + (size_t)(m0 + r) * lda + kb + kc, &As[r * BK + kc]);
        }
#pragma unroll
        for (int i = 0; i < nB; i++) {
            int c = i * 256 + tid;
            int r = c / CPR, kc = (c % CPR) * 8;
            load16_lds(Bw + (size_t)(n0 + r) * ldb + kb + kc, &Bs[r * BK + kc]);
        }
        __syncthreads();
#pragma unroll
        for (int kk = 0; kk < BK / 32; kk++) {
            short8 af[TM], bfr[TN];
#pragma unroll
            for (int t = 0; t < TM; t++)
                af[t] = *reinterpret_cast<const short8*>(&As[(wm + t * 16 + l16) * BK + kk * 32 + quad * 8]);
#pragma unroll
            for (int u2 = 0; u2 < TN; u2++)
                bfr[u2] = *reinterpret_cast<const short8*>(&Bs[(wn + u2 * 16 + l16) * BK + kk * 32 + quad * 8]);
#pragma unroll
            for (int t = 0; t < TM; t++)
#pragma unroll
                for (int u2 = 0; u2 < TN; u2++)
                    acc[t][u2] = __builtin_amdgcn_mfma_f32_16x16x32_bf16(af[t], bfr[u2], acc[t][u2], 0, 0, 0);
        }
    }

#pragma unroll
    for (int t = 0; t < TM; t++) {
#pragma unroll
        for (int u2 = 0; u2 < TN; u2++) {
#pragma unroll
            for (int r = 0; r < 4; r++) {
                int row = m0 + wm + t * 16 + quad * 4 + r;
                int col = n0 + wn + u2 * 16 + l16;
                float val = acc[t][u2][r];
                if (EPI == EPI_SPLIT) {
                    val += bias[col];
                    if (col < 2048) {
                        out0[(size_t)row * 2048 + col] = val;
                    } else {
                        // gate half: pre-apply silu, store bf16
                        float sr = val / (1.f + __expf(-val));
                        outb[(size_t)row * 2048 + col - 2048] = f2bf(sr);
                    }
                } else if (EPI == EPI_SOFTPLUS) {
                    val += bias[col];
                    float sp = fmaxf(val, 0.f) + __logf(1.f + __expf(-fabsf(val)));
                    out0[(size_t)row * N + col] = sp;
                } else if (EPI == EPI_OUT) {
                    val += bias[col];
                    out0[(size_t)row * N + col] = val;
                } else { // EPI_PARTIAL: split-K partials [ks][m][96]
                    out0[((size_t)ks * 2048 + row) * 96 + col] = val;
                }
            }
        }
    }
}

// depthwise causal conv (k=3) + silu. fp32 in, bf16 out.
__global__ __launch_bounds__(256)
void conv_silu(const float* __restrict__ xc, const float* __restrict__ cw,
               const float* __restrict__ cb, ushort_t* __restrict__ ub)
{
    int id = blockIdx.x * 256 + threadIdx.x;   // 2048 * 512
    int m  = id >> 9;
    int d4 = (id & 511) * 4;
    int l  = m & 1023;

    const float4 zero = make_float4(0.f, 0.f, 0.f, 0.f);
    float4 a = *reinterpret_cast<const float4*>(xc + (size_t)m * 2048 + d4);
    float4 b = (l >= 1) ? *reinterpret_cast<const float4*>(xc + (size_t)(m - 1) * 2048 + d4) : zero;
    float4 c = (l >= 2) ? *reinterpret_cast<const float4*>(xc + (size_t)(m - 2) * 2048 + d4) : zero;

    float av[4] = {a.x, a.y, a.z, a.w};
    float bv[4] = {b.x, b.y, b.z, b.w};
    float cv[4] = {c.x, c.y, c.z, c.w};
    union { ushort_t u[4]; uint2 q; } o;
#pragma unroll
    for (int j = 0; j < 4; j++) {
        int d = d4 + j;
        float v = cb[d] + cw[d * 3 + 0] * cv[j] + cw[d * 3 + 1] * bv[j] + cw[d * 3 + 2] * av[j];
        o.u[j] = f2bf(v / (1.f + __expf(-v)));
    }
    *reinterpret_cast<uint2*>(ub + (size_t)m * 2048 + d4) = o.q;
}

// reduce split-K=4 partials -> xp fp32 (2048 x 96) and dlt bf16 (2048 x 64)
__global__ __launch_bounds__(256)
void xp_reduce(const float* __restrict__ part, float* __restrict__ xp, ushort_t* __restrict__ dltb)
{
    int e = blockIdx.x * 256 + threadIdx.x;    // < 2048*96 exactly
    float s = 0.f;
#pragma unroll
    for (int ks = 0; ks < 4; ks++) s += part[(size_t)ks * 2048 * 96 + e];
    xp[e] = s;
    int n = e % 96, m = e / 96;
    if (n < 64) dltb[(size_t)m * 64 + n] = f2bf(s);
}

// Chunked selective scan, wave-parallel over time, occupancy-optimized.
// Block = 512 thr = 8 waves; block covers one 256-token chunk x 16 channels.
// lane&15 = channel, lane>>4 = state-quad q (4 of 16 states). Wave w owns
// timesteps [32w, 32w+32). Segmented affine scan:
//  phase 1: local scan from 0 -> segment outputs q_v + sum(delta) per segment
//  phase 2: carry s_in(w) = sum_{v<w} exp(A*cum)*q_v  (decay prod == exp(A*sum dv))
//  phase 3: replay with carry; y = sum_n s_n*C_n (2-hop shfl); gate with
//           pre-computed silu(res) (bf16); store bf16 yg.
__global__ __launch_bounds__(512, 6)
void scan_kernel(const float* __restrict__ delta, const ushort_t* __restrict__ ub,
                 const float* __restrict__ xp, const float* __restrict__ A_log,
                 const ushort_t* __restrict__ sgb, ushort_t* __restrict__ ygb)
{
    __shared__ __align__(16) float Bsh[256 * 16];
    __shared__ __align__(16) float Csh[256 * 16];
    __shared__ float sQ[8][16][17];
    __shared__ float sS[8][16];

    const int tid  = threadIdx.x;
    const int w    = tid >> 6;                // wave 0..7
    const int lane = tid & 63;
    const int dl   = lane & 15;               // channel within tile
    const int q    = lane >> 4;               // state quad: n in [4q, 4q+4)
    const int d    = blockIdx.x * 16 + dl;
    const int c    = blockIdx.y;              // (batch<<2)|chunk
    const int mbase = (c >> 2) * 1024 + (c & 3) * 256;

    {   // stage B (xp cols 64..79) / C (80..95): row = tid>>1, half = tid&1
        int r = tid >> 1, hf = tid & 1;
        const float4* rp4 = reinterpret_cast<const float4*>(xp + (size_t)(mbase + r) * 96 + 64 + hf * 16);
        float* dst = (hf ? Csh : Bsh) + r * 16;
        reinterpret_cast<float4*>(dst)[0] = rp4[0];
        reinterpret_cast<float4*>(dst)[1] = rp4[1];
        reinterpret_cast<float4*>(dst)[2] = rp4[2];
        reinterpret_cast<float4*>(dst)[3] = rp4[3];
    }

    float Av[4];
    {
        float4 a0 = *reinterpret_cast<const float4*>(A_log + (size_t)d * 16 + q * 4);
        Av[0] = -__expf(a0.x); Av[1] = -__expf(a0.y);
        Av[2] = -__expf(a0.z); Av[3] = -__expf(a0.w);
    }

    float s[4] = {0.f, 0.f, 0.f, 0.f};
    float sumdv = 0.f;
    const int t0 = w * 32;
    __syncthreads();

    // phase 1: local segment scan (s_in = 0)
#pragma unroll 4
    for (int tt = 0; tt < 32; tt++) {
        int t = t0 + tt;
        size_t idx = (size_t)(mbase + t) * 2048 + d;
        float dvv = delta[idx];
        float uv  = bf2f(ub[idx]);
        float dvu = dvv * uv;
        sumdv += dvv;
        const float* Brow = &Bsh[t * 16 + q * 4];
#pragma unroll
        for (int n = 0; n < 4; n++) {
            float dA = __expf(dvv * Av[n]);
            s[n] = fmaf(dA, s[n], dvu * Brow[n]);
        }
    }
#pragma unroll
    for (int n = 0; n < 4; n++) sQ[w][dl][q * 4 + n] = s[n];
    if (q == 0) sS[w][dl] = sumdv;
    __syncthreads();

    // phase 2: compose carry from lower segments
    {
        float sin_[4] = {0.f, 0.f, 0.f, 0.f};
        float cum = 0.f;
        for (int v = w - 1; v >= 0; v--) {
#pragma unroll
            for (int n = 0; n < 4; n++)
                sin_[n] += __expf(Av[n] * cum) * sQ[v][dl][q * 4 + n];
            cum += sS[v][dl];
        }
#pragma unroll
        for (int n = 0; n < 4; n++) s[n] = sin_[n];
    }

    // phase 3: replay with carry, emit gated y
#pragma unroll 2
    for (int tt = 0; tt < 32; tt++) {
        int t = t0 + tt;
        size_t idx = (size_t)(mbase + t) * 2048 + d;
        float dvv = delta[idx];
        float uv  = bf2f(ub[idx]);
        float dvu = dvv * uv;
        const float* Brow = &Bsh[t * 16 + q * 4];
        const float* Crow = &Csh[t * 16 + q * 4];
        float y = 0.f;
#pragma unroll
        for (int n = 0; n < 4; n++) {
            float dA = __expf(dvv * Av[n]);
            s[n] = fmaf(dA, s[n], dvu * Brow[n]);
            y = fmaf(s[n], Crow[n], y);
        }
        y += __shfl_xor(y, 16);
        y += __shfl_xor(y, 32);
        if (q == 0) {
            float sr = bf2f(sgb[idx]);
            ygb[idx] = f2bf(y * sr);
        }
    }
}

extern "C" void kernel_launch(void* const* d_in, const int* in_sizes, int n_in,
                              void* d_out, int out_size, void* d_ws, size_t ws_size,
                              hipStream_t stream)
{
    const float* x      = (const float*)d_in[0];   // (2,1024,1024) fp32
    const float* W_in   = (const float*)d_in[1];   // (4096,1024)
    const float* b_in   = (const float*)d_in[2];   // (4096,)
    const float* conv_w = (const float*)d_in[3];   // (2048,1,3)
    const float* conv_b = (const float*)d_in[4];   // (2048,)
    const float* W_x    = (const float*)d_in[5];   // (96,2048)
    const float* W_dt   = (const float*)d_in[6];   // (2048,64)
    const float* b_dt   = (const float*)d_in[7];   // (2048,)
    const float* A_log  = (const float*)d_in[8];   // (2048,16)
    const float* W_out  = (const float*)d_in[9];   // (1024,2048)
    const float* b_out  = (const float*)d_in[10];  // (1024,)
    float* out = (float*)d_out;                    // (2,1024,1024) fp32

    // Workspace ~53 MB. delta aliases xc (dead after conv).
    char* p = (char*)d_ws;
    auto alloc = [&](size_t bytes) { char* r = p; p += (bytes + 255) & ~(size_t)255; return r; };
    ushort_t* xbf    = (ushort_t*)alloc(2048ull * 1024 * 2);   // 4 MB
    ushort_t* winbf  = (ushort_t*)alloc(4096ull * 1024 * 2);   // 8 MB
    ushort_t* wxbf   = (ushort_t*)alloc(96ull * 2048 * 2);
    ushort_t* wdtbf  = (ushort_t*)alloc(2048ull * 64 * 2);
    ushort_t* woutbf = (ushort_t*)alloc(1024ull * 2048 * 2);   // 4 MB
    float*    xc     = (float*)alloc(2048ull * 2048 * 4);      // 16 MB (later: delta)
    ushort_t* sgb    = (ushort_t*)alloc(2048ull * 2048 * 2);   // 8 MB  silu(res) bf16
    ushort_t* ub     = (ushort_t*)alloc(2048ull * 2048 * 2);   // 8 MB
    float*    xpp    = (float*)alloc(4ull * 2048 * 96 * 4);    // 3 MB (split-K=4)
    float*    xp     = (float*)alloc(2048ull * 96 * 4);
    ushort_t* dltb   = (ushort_t*)alloc(2048ull * 64 * 2);
    ushort_t* ygb    = (ushort_t*)alloc(2048ull * 2048 * 2);   // 8 MB
    float*    delta  = xc;                                     // alias

    // 0. round x + weights to bf16
    cvt5<<<8512, 256, 0, stream>>>(x, W_in, W_x, W_dt, W_out,
                                   xbf, winbf, wxbf, wdtbf, woutbf);

    // 1. in_proj: xr = x @ W_in^T + b_in -> xc fp32 | silu(res) bf16
    gemm_bt<128, 128, 64, 2, 2, EPI_SPLIT><<<dim3(16, 32), 256, 0, stream>>>(
        xbf, 1024, winbf, 1024, xc, nullptr, sgb, b_in, 4096, 1024);

    // 2. depthwise causal conv + silu -> ub (bf16)
    conv_silu<<<4096, 256, 0, stream>>>(xc, conv_w, conv_b, ub);

    // 3. x_proj: xp = u @ W_x^T (split-K=4, fp32 partials)
    gemm_bt<64, 96, 64, 4, 1, EPI_PARTIAL><<<dim3(32, 1, 4), 256, 0, stream>>>(
        ub, 2048, wxbf, 2048, xpp, nullptr, nullptr, nullptr, 96, 512);

    // 4. reduce partials -> xp fp32, dlt bf16
    xp_reduce<<<768, 256, 0, stream>>>(xpp, xp, dltb);

    // 5. dt_proj: delta = softplus(dlt @ W_dt^T + b_dt) (fp32, overwrites xc)
    gemm_bt<64, 64, 64, 2, 2, EPI_SOFTPLUS><<<dim3(32, 32), 256, 0, stream>>>(
        dltb, 64, wdtbf, 64, delta, nullptr, nullptr, b_dt, 2048, 64);

    // 6. wave-parallel chunked scan + gate -> ygb (bf16)
    scan_kernel<<<dim3(128, 8), 512, 0, stream>>>(delta, ub, xp, A_log, sgb, ygb);

    // 7. out_proj: out = yg @ W_out^T + b_out (fp32 out)
    gemm_bt<128, 64, 64, 2, 2, EPI_OUT><<<dim3(16, 16), 256, 0, stream>>>(
        ygb, 2048, woutbf, 2048, out, nullptr, nullptr, b_out, 1024, 2048);
}

// Round 9
// 236.454 us; speedup vs baseline: 3.4169x; 1.0843x over previous
//
#include <hip/hip_runtime.h>
#include <stdint.h>
#include <stddef.h>

typedef __attribute__((ext_vector_type(8))) short short8;
typedef __attribute__((ext_vector_type(4))) float floatx4;
typedef unsigned short ushort_t;

__device__ __forceinline__ ushort_t f2bf(float f) {
    union { float f; uint32_t u; } v; v.f = f;
    return (ushort_t)((v.u + 0x7fffu + ((v.u >> 16) & 1u)) >> 16);
}
__device__ __forceinline__ float bf2f(ushort_t u) {
    union { uint32_t u; float f; } v; v.u = ((uint32_t)u) << 16; return v.f;
}

// async global->LDS 16B staging (m97). LDS dest = wave-uniform base + lane*16.
__device__ __forceinline__ void load16_lds(const ushort_t* g, short* l) {
    __builtin_amdgcn_global_load_lds((const __attribute__((address_space(1))) void*)g,
                                     (__attribute__((address_space(3))) void*)l, 16, 0, 0);
}

enum { EPI_SPLIT = 0, EPI_SOFTPLUS = 1, EPI_OUT = 2, EPI_PARTIAL = 3 };

// Convert x + 4 weights fp32 -> bf16 in one launch.
__global__ __launch_bounds__(256)
void cvt5(const float* __restrict__ x, const float* __restrict__ win,
          const float* __restrict__ wx, const float* __restrict__ wdt,
          const float* __restrict__ wout,
          ushort_t* __restrict__ xb, ushort_t* __restrict__ winb,
          ushort_t* __restrict__ wxb, ushort_t* __restrict__ wdtb,
          ushort_t* __restrict__ woutb)
{
    int g = blockIdx.x * 256 + threadIdx.x;   // < 2179072 exactly
    const float* s; ushort_t* d; int off;
    if      (g < 524288)  { s = x;    d = xb;    off = g; }
    else if (g < 1572864) { s = win;  d = winb;  off = g - 524288; }
    else if (g < 1622016) { s = wx;   d = wxb;   off = g - 1572864; }
    else if (g < 1654784) { s = wdt;  d = wdtb;  off = g - 1622016; }
    else                  { s = wout; d = woutb; off = g - 1654784; }
    float4 v = reinterpret_cast<const float4*>(s)[off];
    union { ushort_t u[4]; uint2 q; } o;
    o.u[0] = f2bf(v.x); o.u[1] = f2bf(v.y); o.u[2] = f2bf(v.z); o.u[3] = f2bf(v.w);
    *reinterpret_cast<uint2*>(d + (size_t)off * 4) = o.q;
}

// C[m,n] = sum_k A[m,k] * B[n,k]  (bf16 operands, fp32 accum)
template<int BM, int BN, int BK, int WR, int WC, int EPI>
__global__ __launch_bounds__(256)
void gemm_bt(const ushort_t* __restrict__ A, int lda,
             const ushort_t* __restrict__ Bw, int ldb,
             float* __restrict__ out0, float* __restrict__ out1,
             ushort_t* __restrict__ outb,
             const float* __restrict__ bias,
             int N, int kchunk)
{
    constexpr int TM = BM / WR / 16;
    constexpr int TN = BN / WC / 16;
    static_assert(BM % (WR * 16) == 0 && BN % (WC * 16) == 0, "tile");
    static_assert((BM * BK) % 2048 == 0 && (BN * BK) % 2048 == 0, "stage");

    __shared__ __align__(16) short As[BM * BK];
    __shared__ __align__(16) short Bs[BN * BK];

    const int tid  = threadIdx.x;
    const int m0   = blockIdx.x * BM;
    const int n0   = blockIdx.y * BN;
    const int ks   = blockIdx.z;
    const int kbeg = ks * kchunk;

    const int w    = tid >> 6;
    const int lane = tid & 63;
    const int quad = lane >> 4;
    const int l16  = lane & 15;
    const int wr   = w / WC, wc = w % WC;
    const int wm   = wr * (BM / WR);
    const int wn   = wc * (BN / WC);

    floatx4 acc[TM][TN];
#pragma unroll
    for (int i = 0; i < TM; i++)
#pragma unroll
        for (int j = 0; j < TN; j++) acc[i][j] = (floatx4){0.f, 0.f, 0.f, 0.f};

    constexpr int nA = BM * BK / 2048;
    constexpr int nB = BN * BK / 2048;
    constexpr int CPR = BK / 8;

    for (int kb = kbeg; kb < kbeg + kchunk; kb += BK) {
        __syncthreads();
#pragma unroll
        for (int i = 0; i < nA; i++) {
            int c = i * 256 + tid;
            int r = c / CPR, kc = (c % CPR) * 8;
            load16_lds(A + (size_t)(m0 + r) * lda + kb + kc, &As[r * BK + kc]);
        }
#pragma unroll
        for (int i = 0; i < nB; i++) {
            int c = i * 256 + tid;
            int r = c / CPR, kc = (c % CPR) * 8;
            load16_lds(Bw + (size_t)(n0 + r) * ldb + kb + kc, &Bs[r * BK + kc]);
        }
        __syncthreads();
#pragma unroll
        for (int kk = 0; kk < BK / 32; kk++) {
            short8 af[TM], bfr[TN];
#pragma unroll
            for (int t = 0; t < TM; t++)
                af[t] = *reinterpret_cast<const short8*>(&As[(wm + t * 16 + l16) * BK + kk * 32 + quad * 8]);
#pragma unroll
            for (int u2 = 0; u2 < TN; u2++)
                bfr[u2] = *reinterpret_cast<const short8*>(&Bs[(wn + u2 * 16 + l16) * BK + kk * 32 + quad * 8]);
#pragma unroll
            for (int t = 0; t < TM; t++)
#pragma unroll
                for (int u2 = 0; u2 < TN; u2++)
                    acc[t][u2] = __builtin_amdgcn_mfma_f32_16x16x32_bf16(af[t], bfr[u2], acc[t][u2], 0, 0, 0);
        }
    }

#pragma unroll
    for (int t = 0; t < TM; t++) {
#pragma unroll
        for (int u2 = 0; u2 < TN; u2++) {
#pragma unroll
            for (int r = 0; r < 4; r++) {
                int row = m0 + wm + t * 16 + quad * 4 + r;
                int col = n0 + wn + u2 * 16 + l16;
                float val = acc[t][u2][r];
                if (EPI == EPI_SPLIT) {
                    val += bias[col];
                    if (col < 2048) {
                        out0[(size_t)row * 2048 + col] = val;
                    } else {
                        float sr = val / (1.f + __expf(-val));
                        outb[(size_t)row * 2048 + col - 2048] = f2bf(sr);
                    }
                } else if (EPI == EPI_SOFTPLUS) {
                    val += bias[col];
                    float sp = fmaxf(val, 0.f) + __logf(1.f + __expf(-fabsf(val)));
                    out0[(size_t)row * N + col] = sp;
                } else if (EPI == EPI_OUT) {
                    val += bias[col];
                    out0[(size_t)row * N + col] = val;
                } else { // EPI_PARTIAL: split-K partials [ks][m][96]
                    out0[((size_t)ks * 2048 + row) * 96 + col] = val;
                }
            }
        }
    }
}

// depthwise causal conv (k=3) + silu. fp32 in, bf16 out.
__global__ __launch_bounds__(256)
void conv_silu(const float* __restrict__ xc, const float* __restrict__ cw,
               const float* __restrict__ cb, ushort_t* __restrict__ ub)
{
    int id = blockIdx.x * 256 + threadIdx.x;   // 2048 * 512
    int m  = id >> 9;
    int d4 = (id & 511) * 4;
    int l  = m & 1023;

    const float4 zero = make_float4(0.f, 0.f, 0.f, 0.f);
    float4 a = *reinterpret_cast<const float4*>(xc + (size_t)m * 2048 + d4);
    float4 b = (l >= 1) ? *reinterpret_cast<const float4*>(xc + (size_t)(m - 1) * 2048 + d4) : zero;
    float4 c = (l >= 2) ? *reinterpret_cast<const float4*>(xc + (size_t)(m - 2) * 2048 + d4) : zero;

    float av[4] = {a.x, a.y, a.z, a.w};
    float bv[4] = {b.x, b.y, b.z, b.w};
    float cv[4] = {c.x, c.y, c.z, c.w};
    union { ushort_t u[4]; uint2 q; } o;
#pragma unroll
    for (int j = 0; j < 4; j++) {
        int d = d4 + j;
        float v = cb[d] + cw[d * 3 + 0] * cv[j] + cw[d * 3 + 1] * bv[j] + cw[d * 3 + 2] * av[j];
        o.u[j] = f2bf(v / (1.f + __expf(-v)));
    }
    *reinterpret_cast<uint2*>(ub + (size_t)m * 2048 + d4) = o.q;
}

// reduce split-K=4 partials -> xp fp32 (2048 x 96) and dlt bf16 (2048 x 64)
__global__ __launch_bounds__(256)
void xp_reduce(const float* __restrict__ part, float* __restrict__ xp, ushort_t* __restrict__ dltb)
{
    int e = blockIdx.x * 256 + threadIdx.x;    // < 2048*96 exactly
    float s = 0.f;
#pragma unroll
    for (int ks = 0; ks < 4; ks++) s += part[(size_t)ks * 2048 * 96 + e];
    xp[e] = s;
    int n = e % 96, m = e / 96;
    if (n < 64) dltb[(size_t)m * 64 + n] = f2bf(s);
}

// Chunked selective scan v3: thread = 1 channel x 8 states.
// Block = 1024 thr = 16 waves, covers one 256-token chunk x 32 channels.
// lane&31 = channel, lane>>5 = state-half h (n in [8h,8h+8)).
// Wave w owns timesteps [16w, 16w+16).  Segmented affine scan:
//  phase 1: local scan from 0 -> per-segment outputs sQ + sum(delta) sS
//  phase 2: carry s_in(w) = sum_{v<w} exp(A*cum)*sQ_v
//  phase 3: replay with carry; y reduced across h by one shfl; gate; store.
// Coalescing: delta 128 B/wave, B/C LDS rows wave-uniform (broadcast).
// Grid 512 blocks x 2/CU = exactly full, 32 waves/CU.
__global__ __launch_bounds__(1024, 8)
void scan_kernel(const float* __restrict__ delta, const ushort_t* __restrict__ ub,
                 const float* __restrict__ xp, const float* __restrict__ A_log,
                 const ushort_t* __restrict__ sgb, ushort_t* __restrict__ ygb)
{
    __shared__ __align__(16) float Bsh[256 * 16];
    __shared__ __align__(16) float Csh[256 * 16];
    __shared__ float sQ[16][32][17];
    __shared__ float sS[16][32];

    const int tid  = threadIdx.x;
    const int w    = tid >> 6;                // wave 0..15 = time segment
    const int lane = tid & 63;
    const int dl   = lane & 31;               // channel within tile
    const int h    = lane >> 5;               // state half
    const int d    = blockIdx.x * 32 + dl;
    const int c    = blockIdx.y;              // (batch<<2)|chunk
    const int mbase = (c >> 2) * 1024 + (c & 3) * 256;

    {   // stage B (xp cols 64..79) / C (80..95): 4 threads per row
        int r = tid >> 2, part = tid & 3;
        const float4* rp = reinterpret_cast<const float4*>(xp + (size_t)(mbase + r) * 96 + 64);
        reinterpret_cast<float4*>(Bsh + r * 16)[part] = rp[part];
        reinterpret_cast<float4*>(Csh + r * 16)[part] = rp[part + 4];
    }

    float Av[8];
    {
        const float4* ap = reinterpret_cast<const float4*>(A_log + (size_t)d * 16 + h * 8);
        float4 a0 = ap[0], a1 = ap[1];
        Av[0] = -__expf(a0.x); Av[1] = -__expf(a0.y); Av[2] = -__expf(a0.z); Av[3] = -__expf(a0.w);
        Av[4] = -__expf(a1.x); Av[5] = -__expf(a1.y); Av[6] = -__expf(a1.z); Av[7] = -__expf(a1.w);
    }

    float s[8];
#pragma unroll
    for (int n = 0; n < 8; n++) s[n] = 0.f;
    float sumdv = 0.f;
    const int t0 = w * 16;
    __syncthreads();

    // phase 1: local segment scan (s_in = 0)
#pragma unroll 4
    for (int tt = 0; tt < 16; tt++) {
        int t = t0 + tt;
        size_t idx = (size_t)(mbase + t) * 2048 + d;
        float dvv = delta[idx];
        float uv  = bf2f(ub[idx]);
        float dvu = dvv * uv;
        sumdv += dvv;
        const float* Brow = &Bsh[t * 16 + h * 8];
#pragma unroll
        for (int n = 0; n < 8; n++) {
            float dA = __expf(dvv * Av[n]);
            s[n] = fmaf(dA, s[n], dvu * Brow[n]);
        }
    }
#pragma unroll
    for (int n = 0; n < 8; n++) sQ[w][dl][h * 8 + n] = s[n];
    if (h == 0) sS[w][dl] = sumdv;
    __syncthreads();

    // phase 2: compose carry from lower segments
    {
        float sin_[8];
#pragma unroll
        for (int n = 0; n < 8; n++) sin_[n] = 0.f;
        float cum = 0.f;
        for (int v = w - 1; v >= 0; v--) {
#pragma unroll
            for (int n = 0; n < 8; n++)
                sin_[n] += __expf(Av[n] * cum) * sQ[v][dl][h * 8 + n];
            cum += sS[v][dl];
        }
#pragma unroll
        for (int n = 0; n < 8; n++) s[n] = sin_[n];
    }

    // phase 3: replay with carry, emit gated y
#pragma unroll 2
    for (int tt = 0; tt < 16; tt++) {
        int t = t0 + tt;
        size_t idx = (size_t)(mbase + t) * 2048 + d;
        float dvv = delta[idx];
        float uv  = bf2f(ub[idx]);
        float dvu = dvv * uv;
        const float* Brow = &Bsh[t * 16 + h * 8];
        const float* Crow = &Csh[t * 16 + h * 8];
        float y = 0.f;
#pragma unroll
        for (int n = 0; n < 8; n++) {
            float dA = __expf(dvv * Av[n]);
            s[n] = fmaf(dA, s[n], dvu * Brow[n]);
            y = fmaf(s[n], Crow[n], y);
        }
        y += __shfl_xor(y, 32);
        if (h == 0) {
            float sr = bf2f(sgb[idx]);
            ygb[idx] = f2bf(y * sr);
        }
    }
}

extern "C" void kernel_launch(void* const* d_in, const int* in_sizes, int n_in,
                              void* d_out, int out_size, void* d_ws, size_t ws_size,
                              hipStream_t stream)
{
    const float* x      = (const float*)d_in[0];   // (2,1024,1024) fp32
    const float* W_in   = (const float*)d_in[1];   // (4096,1024)
    const float* b_in   = (const float*)d_in[2];   // (4096,)
    const float* conv_w = (const float*)d_in[3];   // (2048,1,3)
    const float* conv_b = (const float*)d_in[4];   // (2048,)
    const float* W_x    = (const float*)d_in[5];   // (96,2048)
    const float* W_dt   = (const float*)d_in[6];   // (2048,64)
    const float* b_dt   = (const float*)d_in[7];   // (2048,)
    const float* A_log  = (const float*)d_in[8];   // (2048,16)
    const float* W_out  = (const float*)d_in[9];   // (1024,2048)
    const float* b_out  = (const float*)d_in[10];  // (1024,)
    float* out = (float*)d_out;                    // (2,1024,1024) fp32

    // Workspace ~53 MB. delta aliases xc (dead after conv).
    char* p = (char*)d_ws;
    auto alloc = [&](size_t bytes) { char* r = p; p += (bytes + 255) & ~(size_t)255; return r; };
    ushort_t* xbf    = (ushort_t*)alloc(2048ull * 1024 * 2);   // 4 MB
    ushort_t* winbf  = (ushort_t*)alloc(4096ull * 1024 * 2);   // 8 MB
    ushort_t* wxbf   = (ushort_t*)alloc(96ull * 2048 * 2);
    ushort_t* wdtbf  = (ushort_t*)alloc(2048ull * 64 * 2);
    ushort_t* woutbf = (ushort_t*)alloc(1024ull * 2048 * 2);   // 4 MB
    float*    xc     = (float*)alloc(2048ull * 2048 * 4);      // 16 MB (later: delta)
    ushort_t* sgb    = (ushort_t*)alloc(2048ull * 2048 * 2);   // 8 MB  silu(res) bf16
    ushort_t* ub     = (ushort_t*)alloc(2048ull * 2048 * 2);   // 8 MB
    float*    xpp    = (float*)alloc(4ull * 2048 * 96 * 4);    // 3 MB (split-K=4)
    float*    xp     = (float*)alloc(2048ull * 96 * 4);
    ushort_t* dltb   = (ushort_t*)alloc(2048ull * 64 * 2);
    ushort_t* ygb    = (ushort_t*)alloc(2048ull * 2048 * 2);   // 8 MB
    float*    delta  = xc;                                     // alias

    // 0. round x + weights to bf16
    cvt5<<<8512, 256, 0, stream>>>(x, W_in, W_x, W_dt, W_out,
                                   xbf, winbf, wxbf, wdtbf, woutbf);

    // 1. in_proj: xr = x @ W_in^T + b_in -> xc fp32 | silu(res) bf16
    gemm_bt<128, 128, 64, 2, 2, EPI_SPLIT><<<dim3(16, 32), 256, 0, stream>>>(
        xbf, 1024, winbf, 1024, xc, nullptr, sgb, b_in, 4096, 1024);

    // 2. depthwise causal conv + silu -> ub (bf16)
    conv_silu<<<4096, 256, 0, stream>>>(xc, conv_w, conv_b, ub);

    // 3. x_proj: xp = u @ W_x^T (split-K=4, fp32 partials)
    gemm_bt<64, 96, 64, 4, 1, EPI_PARTIAL><<<dim3(32, 1, 4), 256, 0, stream>>>(
        ub, 2048, wxbf, 2048, xpp, nullptr, nullptr, nullptr, 96, 512);

    // 4. reduce partials -> xp fp32, dlt bf16
    xp_reduce<<<768, 256, 0, stream>>>(xpp, xp, dltb);

    // 5. dt_proj: delta = softplus(dlt @ W_dt^T + b_dt) (fp32, overwrites xc)
    gemm_bt<64, 64, 64, 2, 2, EPI_SOFTPLUS><<<dim3(32, 32), 256, 0, stream>>>(
        dltb, 64, wdtbf, 64, delta, nullptr, nullptr, b_dt, 2048, 64);

    // 6. wave-parallel chunked scan + gate -> ygb (bf16)
    scan_kernel<<<dim3(64, 8), 1024, 0, stream>>>(delta, ub, xp, A_log, sgb, ygb);

    // 7. out_proj: out = yg @ W_out^T + b_out (fp32 out)
    gemm_bt<128, 64, 64, 2, 2, EPI_OUT><<<dim3(16, 16), 256, 0, stream>>>(
        ygb, 2048, woutbf, 2048, out, nullptr, nullptr, b_out, 1024, 2048);
}